// Round 1
// 784.673 us; speedup vs baseline: 1.0053x; 1.0053x over previous
//
#include <hip/hip_runtime.h>
#include <math.h>

// B=8, L=8192, W=128, MODES=32, NL=4, SEG=4 (seglen 2048), CM=8, H1=128

// ---------------- workspace layout (in floats) ----------------
#define OFF_COSTAB 0
#define OFF_SINTAB 8192
#define OFF_BASTC  16384                     // [32][8192]  cos(2*pi*k*l/L)
#define OFF_BASTS  (OFF_BASTC + 262144)      // [32][8192]  sin  (contiguous -> [64][8192])
#define OFF_UNUSED (OFF_BASTS + 262144)
#define OFF_WBAR   (OFF_UNUSED + 65536)      // [NL][SEG][CM][W]
#define OFF_HFP    (OFF_WBAR + 16384)        // (unused now)
#define OFF_HF     (OFF_HFP + 1048576)       // [1024][64]
#define OFF_CH     (OFF_HF + 65536)          // (unused now; rec fused)
#define OFF_REC    (OFF_CH + 32768)          // [8*128][4]
#define OFF_OMCT   (OFF_REC + 4096)          // [8][32 k][128 o]
#define OFF_OMST   (OFF_OMCT + 32768)        // [8][32 k][128 o]
#define OFF_CG     (OFF_OMST + 32768)        // [8][4][128]
#define OFF_MNMX   (OFF_CG + 4096)           // 8 uints
#define OFF_H      (OFF_MNMX + 16)           // [8][128][8192]

__device__ __forceinline__ unsigned int enc_f(float f) {
    unsigned int u = __float_as_uint(f);
    return (u & 0x80000000u) ? ~u : (u | 0x80000000u);
}
__device__ __forceinline__ float dec_f(unsigned int u) {
    return (u & 0x80000000u) ? __uint_as_float(u ^ 0x80000000u) : __uint_as_float(~u);
}
__device__ __forceinline__ float gelu_f(float x) {
    return 0.5f * x * (1.0f + erff(x * 0.70710678118654752f));
}
__device__ __forceinline__ float sigmoid_f(float x) {
    return 1.0f / (1.0f + expf(-x));
}

// cos/sin(2*pi*m/32) compile-time tables (fold to literals in unrolled FMAs)
constexpr float C32T[32] = {
    1.0f,          0.980785280f,  0.923879533f,  0.831469612f,
    0.707106781f,  0.555570233f,  0.382683432f,  0.195090322f,
    0.0f,         -0.195090322f, -0.382683432f, -0.555570233f,
   -0.707106781f, -0.831469612f, -0.923879533f, -0.980785280f,
   -1.0f,         -0.980785280f, -0.923879533f, -0.831469612f,
   -0.707106781f, -0.555570233f, -0.382683432f, -0.195090322f,
    0.0f,          0.195090322f,  0.382683432f,  0.555570233f,
    0.707106781f,  0.831469612f,  0.923879533f,  0.980785280f};
constexpr float S32T[32] = {
    0.0f,          0.195090322f,  0.382683432f,  0.555570233f,
    0.707106781f,  0.831469612f,  0.923879533f,  0.980785280f,
    1.0f,          0.980785280f,  0.923879533f,  0.831469612f,
    0.707106781f,  0.555570233f,  0.382683432f,  0.195090322f,
    0.0f,         -0.195090322f, -0.382683432f, -0.555570233f,
   -0.707106781f, -0.831469612f, -0.923879533f, -0.980785280f,
   -1.0f,         -0.980785280f, -0.923879533f, -0.831469612f,
   -0.707106781f, -0.555570233f, -0.382683432f, -0.195090322f};

// ---------------- init ----------------
__global__ void k_tab(float* ws) {
    int m = blockIdx.x * 256 + threadIdx.x;
    if (m < 8192) {
        double a = (double)m * (6.283185307179586476925286766559 / 8192.0);
        ws[OFF_COSTAB + m] = (float)cos(a);
        ws[OFF_SINTAB + m] = (float)sin(a);
    }
}

__global__ void k_init2(float* ws, const float* __restrict__ cheb_w) {
    int tid = blockIdx.x * 256 + threadIdx.x;
    if (tid < 524288) {
        int j = tid >> 13, l = tid & 8191;
        int k = j & 31;
        int tab = (j < 32) ? OFF_COSTAB : OFF_SINTAB;
        ws[OFF_BASTC + tid] = ws[tab + ((k * l) & 8191)];
    } else if (tid < 524288 + 16384) {
        int r = tid - 524288;           // ((layer*4+s)*8+m)*128 + c
        int c = r & 127;
        int smi = r >> 7;
        const float* wp = cheb_w + ((long)smi * 128 + c) * 128;
        float s = 0.0f;
        for (int o = 0; o < 128; o++) s += wp[o];
        ws[OFF_WBAR + r] = s * (1.0f / 128.0f);
    } else if (tid < 524288 + 16384 + 8) {
        int r = tid - (524288 + 16384);
        unsigned int* mm = (unsigned int*)(ws + OFF_MNMX);
        mm[r] = (r < 4) ? 0xFFFFFFFFu : 0u;
    }
}

// ---------------- fc0 + seg min/max ----------------
__global__ __launch_bounds__(256) void k_fc0(float* ws, const float* __restrict__ x,
                                             const float* __restrict__ w,
                                             const float* __restrict__ bias) {
    int bid = blockIdx.x;
    int b = bid >> 5;
    int l0 = (bid & 31) * 256;
    int t = threadIdx.x;
    int l = l0 + t;
    float x0 = x[((long)b * 8192 + l) * 2];
    float x1 = x[((long)b * 8192 + l) * 2 + 1];
    float* hb = ws + OFF_H + (long)b * 128 * 8192;
    float mn = 1e30f, mx = -1e30f;
    for (int c = 0; c < 128; c++) {
        float v = fmaf(x0, w[c], fmaf(x1, w[128 + c], bias[c]));
        hb[(long)c * 8192 + l] = v;
        mn = fminf(mn, v); mx = fmaxf(mx, v);
    }
    for (int off = 32; off; off >>= 1) {
        mn = fminf(mn, __shfl_down(mn, off));
        mx = fmaxf(mx, __shfl_down(mx, off));
    }
    __shared__ float rmn[4], rmx[4];
    if ((t & 63) == 0) { rmn[t >> 6] = mn; rmx[t >> 6] = mx; }
    __syncthreads();
    if (t == 0) {
        for (int w2 = 1; w2 < 4; w2++) { mn = fminf(mn, rmn[w2]); mx = fmaxf(mx, rmx[w2]); }
        unsigned int* mm = (unsigned int*)(ws + OFF_MNMX);
        int seg = l0 >> 11;
        atomicMin(&mm[seg], enc_f(mn));
        atomicMax(&mm[4 + seg], enc_f(mx));
    }
}

// ---------------- fused DFT(32 modes) + Chebyshev coeffs + rec ----------------
// Factor l = 256*a + t (a<32, t<256).  Per row:
//   inner 32-pt real DFT over a (Hermitian-folded, literal coefficients),
//   twiddle combine over r=t via costab/sintab, block-reduce 64 outputs.
// Cheb coefficients fall out of the same ha[] registers; rec epilogue fused.
__global__ __launch_bounds__(256, 4) void k_dftcb(float* ws, int layer) {
    int row = blockIdx.x;              // b*128 + c
    int t = threadIdx.x;               // r = 0..255
    const float* hr = ws + OFF_H + (long)row * 8192;
    __shared__ float red[4][96];
    int wv = t >> 6;

    float ha[32];
    #pragma unroll
    for (int a = 0; a < 32; a++) ha[a] = hr[a * 256 + t];

    // ---- Chebyshev coefficients (fused k_cheb); seg of l=256a+t is a>>3 ----
    const unsigned int* mm = (const unsigned int*)(ws + OFF_MNMX);
    #pragma unroll
    for (int s = 0; s < 4; s++) {
        float mn = dec_f(mm[s]), mx = dec_f(mm[4 + s]);
        float sc = 2.0f / (mx - mn);
        float acc[8] = {};
        #pragma unroll
        for (int e = 0; e < 8; e++) {
            float xn = (ha[s * 8 + e] - mn) * sc - 1.0f;
            float tpp = 1.0f, tp = xn;
            acc[0] += xn;
            acc[1] += xn * xn;
            #pragma unroll
            for (int mI = 2; mI < 8; mI++) {
                float tn = 2.0f * xn * tp - tpp;
                acc[mI] += xn * tn;
                tpp = tp; tp = tn;
            }
        }
        #pragma unroll
        for (int mI = 0; mI < 8; mI++) {
            float v = acc[mI];
            for (int off = 32; off; off >>= 1) v += __shfl_down(v, off);
            if ((t & 63) == 0) red[wv][64 + s * 8 + mI] = v;
        }
    }

    // ---- inner 32-point real DFT over a, folded a<->32-a ----
    float ep[16], em[16];
    #pragma unroll
    for (int a = 1; a < 16; a++) { ep[a] = ha[a] + ha[32 - a]; em[a] = ha[a] - ha[32 - a]; }
    float h0 = ha[0], h16 = ha[16];
    float Ca[17], Sa[17];
    #pragma unroll
    for (int k = 0; k <= 16; k++) {
        float ca = (k & 1) ? (h0 - h16) : (h0 + h16);
        float sa = 0.0f;
        #pragma unroll
        for (int a = 1; a < 16; a++) {
            ca = fmaf(ep[a], C32T[(k * a) & 31], ca);
            sa = fmaf(em[a], S32T[(k * a) & 31], sa);
        }
        Ca[k] = ca; Sa[k] = sa;
    }
    // Hermitian: Ca[32-k]=Ca[k], Sa[32-k]=-Sa[k]

    // ---- twiddle by theta = 2*pi*k*t/8192 and block-reduce ----
    const float* ct = ws + OFF_COSTAB;
    const float* st = ws + OFF_SINTAB;
    #pragma unroll
    for (int k0 = 0; k0 < 32; k0 += 8) {
        float xr[8], xi[8];
        #pragma unroll
        for (int q = 0; q < 8; q++) {
            int k = k0 + q;
            float caf = (k <= 16) ? Ca[k] : Ca[32 - k];
            float saf = (k <= 16) ? Sa[k] : -Sa[32 - k];
            float c = ct[(k * t) & 8191];
            float s = st[(k * t) & 8191];
            xr[q] = caf * c - saf * s;               // partial of sum h*cos
            xi[q] = fmaf(saf, c, caf * s);           // partial of sum h*sin
        }
        #pragma unroll
        for (int q = 0; q < 8; q++) {
            float a = xr[q], b2 = xi[q];
            for (int off = 32; off; off >>= 1) {
                a += __shfl_down(a, off);
                b2 += __shfl_down(b2, off);
            }
            if ((t & 63) == 0) { red[wv][k0 + q] = a; red[wv][32 + k0 + q] = b2; }
        }
    }
    __syncthreads();
    if (t < 96) {
        float s4 = red[0][t] + red[1][t] + red[2][t] + red[3][t];
        if (t < 64) {
            ws[OFF_HF + (long)row * 64 + t] = s4;    // [k]=cos-sum, [32+k]=sin-sum
        } else {
            red[0][t] = s4 * (1.0f / 2048.0f);       // scaled Cheb coeff, kept in LDS
        }
    }
    __syncthreads();
    // ---- rec = tanh(C . wbar) (fused k_b1) ----
    if (t < 4) {
        const float* wb = ws + OFF_WBAR + ((layer * 4 + t) * 8) * 128 + (row & 127);
        float a = 0.0f;
        #pragma unroll
        for (int mI = 0; mI < 8; mI++) a = fmaf(red[0][64 + t * 8 + mI], wb[mI * 128], a);
        ws[OFF_REC + (long)row * 4 + t] = tanhf(a);
    }
}

// ---------------- B2: mode mix -> omT (k-major); cgate; reset minmax ----------------
__global__ void k_b2(float* ws, const float* __restrict__ swr, const float* __restrict__ swi,
                     const float* __restrict__ gw, const float* __restrict__ gb, int layer) {
    int tid = blockIdx.x * 256 + threadIdx.x;
    if (tid < 32768) {
        int b = tid >> 12, o = (tid >> 5) & 127, k = tid & 31;
        const float* hfb = ws + OFF_HF + (long)b * 8192;  // [128][64]
        const float* wr = swr + (long)layer * 524288 + (long)o * 32 + k;
        const float* wi = swi + (long)layer * 524288 + (long)o * 32 + k;
        float omr = 0.0f, omi = 0.0f;
        for (int i = 0; i < 128; i++) {
            float hr = hfb[i * 64 + k];
            float hs = hfb[i * 64 + 32 + k];
            float wrv = wr[(long)i * 4096], wiv = wi[(long)i * 4096];
            omr = fmaf(hr, wrv, fmaf(hs, wiv, omr));
            omi = fmaf(hr, wiv, fmaf(-hs, wrv, omi));
        }
        float ck = (k == 0) ? (1.0f / 8192.0f) : (2.0f / 8192.0f);
        ws[OFF_OMCT + ((long)b * 32 + k) * 128 + o] = ck * omr;
        ws[OFF_OMST + ((long)b * 32 + k) * 128 + o] = -ck * omi;
    } else if (tid < 32768 + 4096) {
        int r = tid - 32768;
        int b = r >> 9, s = (r >> 7) & 3, o = r & 127;
        float a = gb[layer * 128 + o];
        const float* recp = ws + OFF_REC + (long)b * 512 + s;
        const float* g2 = gw + (long)layer * 32768 + 16384 + o;
        for (int c = 0; c < 128; c++) a = fmaf(recp[c * 4], g2[c * 128], a);
        ws[OFF_CG + (long)(b * 4 + s) * 128 + o] = a;
    }
    if (blockIdx.x == gridDim.x - 1 && threadIdx.x < 8) {
        unsigned int* mm = (unsigned int*)(ws + OFF_MNMX);
        mm[threadIdx.x] = (threadIdx.x < 4) ? 0xFFFFFFFFu : 0u;
    }
}

// ---------------- fused layer: irfft + conv + gelu + gate + update (in place) ----------------
// 512 threads: per thread 4 channels x 4 positions -> 8 waves/SIMD (was 4),
// same 1024 blocks / same LDS tile / same per-block L2 weight traffic.
__global__ __launch_bounds__(512, 8) void k_fuse(float* ws, const float* __restrict__ cw,
                                                 const float* __restrict__ cb,
                                                 const float* __restrict__ gw, int layer) {
    __shared__ float hx[128 * 68];
    __shared__ float rmn[8], rmx[8];
    int bid = blockIdx.x;
    int b = bid >> 7;
    int tile = bid & 127;
    int l0 = tile * 64;
    int seg = l0 >> 11;
    int t = threadIdx.x;
    float* hb = ws + OFF_H + (long)b * 1048576;

    #pragma unroll
    for (int i = 0; i < 4; i++) {
        int idx = t + i * 512;
        int row = idx >> 4, c4 = (idx & 15) * 4;
        *(float4*)&hx[row * 68 + c4] = *(const float4*)&hb[(long)row * 8192 + l0 + c4];
    }
    __syncthreads();

    int m = t & 15, cg = t >> 4;
    int p0 = m * 4, c0 = cg * 4;
    float acc[4][4] = {};

    // inverse DFT (32 modes)
    const float* btc = ws + OFF_BASTC + l0 + p0;
    const float* bts = ws + OFF_BASTS + l0 + p0;
    const float* omc = ws + OFF_OMCT + (long)b * 4096 + c0;
    const float* oms = ws + OFF_OMST + (long)b * 4096 + c0;
    for (int k = 0; k < 32; k++) {
        float4 bc = *(const float4*)&btc[k * 8192];
        float4 bsn = *(const float4*)&bts[k * 8192];
        float4 oc = *(const float4*)&omc[k * 128];
        float4 os = *(const float4*)&oms[k * 128];
        float cv[4] = {bc.x, bc.y, bc.z, bc.w};
        float sv[4] = {bsn.x, bsn.y, bsn.z, bsn.w};
        float ocv[4] = {oc.x, oc.y, oc.z, oc.w};
        float osv[4] = {os.x, os.y, os.z, os.w};
        #pragma unroll
        for (int i = 0; i < 4; i++)
            #pragma unroll
            for (int p = 0; p < 4; p++)
                acc[i][p] = fmaf(ocv[i], cv[p], fmaf(osv[i], sv[p], acc[i][p]));
    }
    // 1x1 conv bypass
    const float* cwt = cw + (long)layer * 16384 + c0;
    for (int j = 0; j < 128; j++) {
        float4 hv = *(const float4*)&hx[j * 68 + p0];
        float4 w0 = *(const float4*)&cwt[j * 128];
        float hvv[4] = {hv.x, hv.y, hv.z, hv.w};
        float wv[4] = {w0.x, w0.y, w0.z, w0.w};
        #pragma unroll
        for (int i = 0; i < 4; i++)
            #pragma unroll
            for (int p = 0; p < 4; p++)
                acc[i][p] = fmaf(hvv[p], wv[i], acc[i][p]);
    }
    // bias + gelu; keep x_fno in regs, publish to LDS (h tile dead)
    float xfr[4][4];
    #pragma unroll
    for (int i = 0; i < 4; i++) {
        float bias = cb[layer * 128 + c0 + i];
        #pragma unroll
        for (int p = 0; p < 4; p++) xfr[i][p] = gelu_f(acc[i][p] + bias);
    }
    __syncthreads();   // all conv reads of h done
    #pragma unroll
    for (int i = 0; i < 4; i++)
        *(float4*)&hx[(c0 + i) * 68 + p0] =
            make_float4(xfr[i][0], xfr[i][1], xfr[i][2], xfr[i][3]);
    __syncthreads();

    // gate GEMM over x_fno
    const float* gwl = gw + (long)layer * 32768 + c0;
    float gac[4][4] = {};
    for (int c = 0; c < 128; c++) {
        float4 xv = *(const float4*)&hx[c * 68 + p0];
        float4 w0 = *(const float4*)&gwl[c * 128];
        float xvv[4] = {xv.x, xv.y, xv.z, xv.w};
        float wv[4] = {w0.x, w0.y, w0.z, w0.w};
        #pragma unroll
        for (int i = 0; i < 4; i++)
            #pragma unroll
            for (int p = 0; p < 4; p++)
                gac[i][p] = fmaf(xvv[p], wv[i], gac[i][p]);
    }
    // epilogue: sigmoid gate, h update, seg min/max
    float mnv = 1e30f, mxv = -1e30f;
    const float* cgp = ws + OFF_CG + (long)(b * 4 + seg) * 128 + c0;
    #pragma unroll
    for (int i = 0; i < 4; i++) {
        float cgv = cgp[i];
        float rv = ws[OFF_REC + (long)(b * 128 + c0 + i) * 4 + seg];
        float v[4];
        #pragma unroll
        for (int p = 0; p < 4; p++) {
            float gg = sigmoid_f(gac[i][p] + cgv);
            v[p] = xfr[i][p] + gg * rv;
            mnv = fminf(mnv, v[p]); mxv = fmaxf(mxv, v[p]);
        }
        *(float4*)&hb[(long)(c0 + i) * 8192 + l0 + p0] = make_float4(v[0], v[1], v[2], v[3]);
    }
    for (int off = 32; off; off >>= 1) {
        mnv = fminf(mnv, __shfl_down(mnv, off));
        mxv = fmaxf(mxv, __shfl_down(mxv, off));
    }
    if ((t & 63) == 0) { rmn[t >> 6] = mnv; rmx[t >> 6] = mxv; }
    __syncthreads();
    if (t == 0) {
        for (int w2 = 1; w2 < 8; w2++) { mnv = fminf(mnv, rmn[w2]); mxv = fmaxf(mxv, rmx[w2]); }
        unsigned int* mm = (unsigned int*)(ws + OFF_MNMX);
        atomicMin(&mm[seg], enc_f(mnv));
        atomicMax(&mm[4 + seg], enc_f(mxv));
    }
}

// ---------------- final fc1(gelu) + fc2 (512 threads, same occupancy fix) -------------
__global__ __launch_bounds__(512, 8) void k_fc12(float* ws, const float* __restrict__ f1w,
                                                 const float* __restrict__ f1b,
                                                 const float* __restrict__ f2w,
                                                 const float* __restrict__ f2b,
                                                 float* __restrict__ out) {
    __shared__ float hx[128 * 68];
    int bid = blockIdx.x;
    int b = bid >> 7;
    int l0 = (bid & 127) * 64;
    int t = threadIdx.x;
    const float* hb = ws + OFF_H + (long)b * 1048576;
    #pragma unroll
    for (int i = 0; i < 4; i++) {
        int idx = t + i * 512;
        int row = idx >> 4, c4 = (idx & 15) * 4;
        *(float4*)&hx[row * 68 + c4] = *(const float4*)&hb[(long)row * 8192 + l0 + c4];
    }
    __syncthreads();
    int m = t & 15, hg = t >> 4;
    int h0 = hg * 4, p0 = m * 4;
    float acc[4][4] = {};
    const float* f1 = f1w + h0;
    for (int c = 0; c < 128; c++) {
        float4 hv = *(const float4*)&hx[c * 68 + p0];
        float4 w0 = *(const float4*)&f1[c * 128];
        float hvv[4] = {hv.x, hv.y, hv.z, hv.w};
        float wv[4] = {w0.x, w0.y, w0.z, w0.w};
        #pragma unroll
        for (int i = 0; i < 4; i++)
            #pragma unroll
            for (int p = 0; p < 4; p++)
                acc[i][p] = fmaf(hvv[p], wv[i], acc[i][p]);
    }
    float outp[4] = {};
    #pragma unroll
    for (int i = 0; i < 4; i++) {
        float bias = f1b[h0 + i];
        float fw = f2w[h0 + i];
        #pragma unroll
        for (int p = 0; p < 4; p++)
            outp[p] = fmaf(fw, gelu_f(acc[i][p] + bias), outp[p]);
    }
    __syncthreads();   // done reading hx; reuse as reduction buffer [32 hg][68]
    *(float4*)&hx[hg * 68 + p0] = make_float4(outp[0], outp[1], outp[2], outp[3]);
    __syncthreads();
    if (t < 64) {
        float s = f2b[0];
        #pragma unroll
        for (int gg = 0; gg < 32; gg++) s += hx[gg * 68 + t];
        out[(long)b * 8192 + l0 + t] = s;
    }
}

extern "C" void kernel_launch(void* const* d_in, const int* in_sizes, int n_in,
                              void* d_out, int out_size, void* d_ws, size_t ws_size,
                              hipStream_t stream) {
    const float* x     = (const float*)d_in[0];
    const float* fc0_w = (const float*)d_in[1];
    const float* fc0_b = (const float*)d_in[2];
    const float* swr   = (const float*)d_in[3];
    const float* swi   = (const float*)d_in[4];
    const float* cw    = (const float*)d_in[5];
    const float* cb    = (const float*)d_in[6];
    const float* chw   = (const float*)d_in[7];
    const float* gw    = (const float*)d_in[8];
    const float* gb    = (const float*)d_in[9];
    const float* f1w   = (const float*)d_in[10];
    const float* f1b   = (const float*)d_in[11];
    const float* f2w   = (const float*)d_in[12];
    const float* f2b   = (const float*)d_in[13];
    float* ws = (float*)d_ws;
    float* out = (float*)d_out;

    k_tab<<<32, 256, 0, stream>>>(ws);
    k_init2<<<2112, 256, 0, stream>>>(ws, chw);
    k_fc0<<<256, 256, 0, stream>>>(ws, x, fc0_w, fc0_b);
    for (int layer = 0; layer < 4; layer++) {
        k_dftcb<<<1024, 256, 0, stream>>>(ws, layer);
        k_b2<<<144, 256, 0, stream>>>(ws, swr, swi, gw, gb, layer);
        k_fuse<<<1024, 512, 0, stream>>>(ws, cw, cb, gw, layer);
    }
    k_fc12<<<1024, 512, 0, stream>>>(ws, f1w, f1b, f2w, f2b, out);
}

// Round 2
// 755.239 us; speedup vs baseline: 1.0445x; 1.0390x over previous
//
#include <hip/hip_runtime.h>
#include <math.h>

// B=8, L=8192, W=128, MODES=32, NL=4, SEG=4 (seglen 2048), CM=8, H1=128

// ---------------- workspace layout (in floats) ----------------
#define OFF_COSTAB 0
#define OFF_SINTAB 8192
#define OFF_BASTC  16384                     // [32][8192]  cos(2*pi*k*l/L)
#define OFF_BASTS  (OFF_BASTC + 262144)      // [32][8192]  sin  (contiguous -> [64][8192])
#define OFF_UNUSED (OFF_BASTS + 262144)
#define OFF_WBAR   (OFF_UNUSED + 65536)      // [NL][SEG][CM][W]
#define OFF_HFP    (OFF_WBAR + 16384)        // (unused now)
#define OFF_HF     (OFF_HFP + 1048576)       // [1024][64]
#define OFF_CH     (OFF_HF + 65536)          // (unused now; rec fused)
#define OFF_REC    (OFF_CH + 32768)          // [8*128][4]
#define OFF_OMCT   (OFF_REC + 4096)          // [8][32 k][128 o]
#define OFF_OMST   (OFF_OMCT + 32768)        // [8][32 k][128 o]
#define OFF_CG     (OFF_OMST + 32768)        // [8][4][128]
#define OFF_MNMX   (OFF_CG + 4096)           // 8 uints
#define OFF_H      (OFF_MNMX + 16)           // [8][128][8192]

__device__ __forceinline__ unsigned int enc_f(float f) {
    unsigned int u = __float_as_uint(f);
    return (u & 0x80000000u) ? ~u : (u | 0x80000000u);
}
__device__ __forceinline__ float dec_f(unsigned int u) {
    return (u & 0x80000000u) ? __uint_as_float(u ^ 0x80000000u) : __uint_as_float(~u);
}
__device__ __forceinline__ float gelu_f(float x) {
    return 0.5f * x * (1.0f + erff(x * 0.70710678118654752f));
}
__device__ __forceinline__ float sigmoid_f(float x) {
    return 1.0f / (1.0f + expf(-x));
}

// cos/sin(2*pi*m/32) compile-time tables (fold to literals in unrolled FMAs)
constexpr float C32T[32] = {
    1.0f,          0.980785280f,  0.923879533f,  0.831469612f,
    0.707106781f,  0.555570233f,  0.382683432f,  0.195090322f,
    0.0f,         -0.195090322f, -0.382683432f, -0.555570233f,
   -0.707106781f, -0.831469612f, -0.923879533f, -0.980785280f,
   -1.0f,         -0.980785280f, -0.923879533f, -0.831469612f,
   -0.707106781f, -0.555570233f, -0.382683432f, -0.195090322f,
    0.0f,          0.195090322f,  0.382683432f,  0.555570233f,
    0.707106781f,  0.831469612f,  0.923879533f,  0.980785280f};
constexpr float S32T[32] = {
    0.0f,          0.195090322f,  0.382683432f,  0.555570233f,
    0.707106781f,  0.831469612f,  0.923879533f,  0.980785280f,
    1.0f,          0.980785280f,  0.923879533f,  0.831469612f,
    0.707106781f,  0.555570233f,  0.382683432f,  0.195090322f,
    0.0f,         -0.195090322f, -0.382683432f, -0.555570233f,
   -0.707106781f, -0.831469612f, -0.923879533f, -0.980785280f,
   -1.0f,         -0.980785280f, -0.923879533f, -0.831469612f,
   -0.707106781f, -0.555570233f, -0.382683432f, -0.195090322f};

// ---------------- init ----------------
__global__ void k_tab(float* ws) {
    int m = blockIdx.x * 256 + threadIdx.x;
    if (m < 8192) {
        double a = (double)m * (6.283185307179586476925286766559 / 8192.0);
        ws[OFF_COSTAB + m] = (float)cos(a);
        ws[OFF_SINTAB + m] = (float)sin(a);
    }
}

__global__ void k_init2(float* ws, const float* __restrict__ cheb_w) {
    int tid = blockIdx.x * 256 + threadIdx.x;
    if (tid < 524288) {
        int j = tid >> 13, l = tid & 8191;
        int k = j & 31;
        int tab = (j < 32) ? OFF_COSTAB : OFF_SINTAB;
        ws[OFF_BASTC + tid] = ws[tab + ((k * l) & 8191)];
    } else if (tid < 524288 + 16384) {
        int r = tid - 524288;           // ((layer*4+s)*8+m)*128 + c
        int c = r & 127;
        int smi = r >> 7;
        const float* wp = cheb_w + ((long)smi * 128 + c) * 128;
        float s = 0.0f;
        for (int o = 0; o < 128; o++) s += wp[o];
        ws[OFF_WBAR + r] = s * (1.0f / 128.0f);
    } else if (tid < 524288 + 16384 + 8) {
        int r = tid - (524288 + 16384);
        unsigned int* mm = (unsigned int*)(ws + OFF_MNMX);
        mm[r] = (r < 4) ? 0xFFFFFFFFu : 0u;
    }
}

// ---------------- fc0 + seg min/max ----------------
__global__ __launch_bounds__(256) void k_fc0(float* ws, const float* __restrict__ x,
                                             const float* __restrict__ w,
                                             const float* __restrict__ bias) {
    int bid = blockIdx.x;
    int b = bid >> 5;
    int l0 = (bid & 31) * 256;
    int t = threadIdx.x;
    int l = l0 + t;
    float x0 = x[((long)b * 8192 + l) * 2];
    float x1 = x[((long)b * 8192 + l) * 2 + 1];
    float* hb = ws + OFF_H + (long)b * 128 * 8192;
    float mn = 1e30f, mx = -1e30f;
    for (int c = 0; c < 128; c++) {
        float v = fmaf(x0, w[c], fmaf(x1, w[128 + c], bias[c]));
        hb[(long)c * 8192 + l] = v;
        mn = fminf(mn, v); mx = fmaxf(mx, v);
    }
    for (int off = 32; off; off >>= 1) {
        mn = fminf(mn, __shfl_down(mn, off));
        mx = fmaxf(mx, __shfl_down(mx, off));
    }
    __shared__ float rmn[4], rmx[4];
    if ((t & 63) == 0) { rmn[t >> 6] = mn; rmx[t >> 6] = mx; }
    __syncthreads();
    if (t == 0) {
        for (int w2 = 1; w2 < 4; w2++) { mn = fminf(mn, rmn[w2]); mx = fmaxf(mx, rmx[w2]); }
        unsigned int* mm = (unsigned int*)(ws + OFF_MNMX);
        int seg = l0 >> 11;
        atomicMin(&mm[seg], enc_f(mn));
        atomicMax(&mm[4 + seg], enc_f(mx));
    }
}

// ---------------- fused DFT(32 modes) + Chebyshev coeffs + rec ----------------
__global__ __launch_bounds__(256, 4) void k_dftcb(float* ws, int layer) {
    int row = blockIdx.x;              // b*128 + c
    int t = threadIdx.x;               // r = 0..255
    const float* hr = ws + OFF_H + (long)row * 8192;
    __shared__ float red[4][96];
    int wv = t >> 6;

    float ha[32];
    #pragma unroll
    for (int a = 0; a < 32; a++) ha[a] = hr[a * 256 + t];

    // ---- Chebyshev coefficients (fused k_cheb); seg of l=256a+t is a>>3 ----
    const unsigned int* mm = (const unsigned int*)(ws + OFF_MNMX);
    #pragma unroll
    for (int s = 0; s < 4; s++) {
        float mn = dec_f(mm[s]), mx = dec_f(mm[4 + s]);
        float sc = 2.0f / (mx - mn);
        float acc[8] = {};
        #pragma unroll
        for (int e = 0; e < 8; e++) {
            float xn = (ha[s * 8 + e] - mn) * sc - 1.0f;
            float tpp = 1.0f, tp = xn;
            acc[0] += xn;
            acc[1] += xn * xn;
            #pragma unroll
            for (int mI = 2; mI < 8; mI++) {
                float tn = 2.0f * xn * tp - tpp;
                acc[mI] += xn * tn;
                tpp = tp; tp = tn;
            }
        }
        #pragma unroll
        for (int mI = 0; mI < 8; mI++) {
            float v = acc[mI];
            for (int off = 32; off; off >>= 1) v += __shfl_down(v, off);
            if ((t & 63) == 0) red[wv][64 + s * 8 + mI] = v;
        }
    }

    // ---- inner 32-point real DFT over a, folded a<->32-a ----
    float ep[16], em[16];
    #pragma unroll
    for (int a = 1; a < 16; a++) { ep[a] = ha[a] + ha[32 - a]; em[a] = ha[a] - ha[32 - a]; }
    float h0 = ha[0], h16 = ha[16];
    float Ca[17], Sa[17];
    #pragma unroll
    for (int k = 0; k <= 16; k++) {
        float ca = (k & 1) ? (h0 - h16) : (h0 + h16);
        float sa = 0.0f;
        #pragma unroll
        for (int a = 1; a < 16; a++) {
            ca = fmaf(ep[a], C32T[(k * a) & 31], ca);
            sa = fmaf(em[a], S32T[(k * a) & 31], sa);
        }
        Ca[k] = ca; Sa[k] = sa;
    }
    // Hermitian: Ca[32-k]=Ca[k], Sa[32-k]=-Sa[k]

    // ---- twiddle by theta = 2*pi*k*t/8192 and block-reduce ----
    const float* ct = ws + OFF_COSTAB;
    const float* st = ws + OFF_SINTAB;
    #pragma unroll
    for (int k0 = 0; k0 < 32; k0 += 8) {
        float xr[8], xi[8];
        #pragma unroll
        for (int q = 0; q < 8; q++) {
            int k = k0 + q;
            float caf = (k <= 16) ? Ca[k] : Ca[32 - k];
            float saf = (k <= 16) ? Sa[k] : -Sa[32 - k];
            float c = ct[(k * t) & 8191];
            float s = st[(k * t) & 8191];
            xr[q] = caf * c - saf * s;               // partial of sum h*cos
            xi[q] = fmaf(saf, c, caf * s);           // partial of sum h*sin
        }
        #pragma unroll
        for (int q = 0; q < 8; q++) {
            float a = xr[q], b2 = xi[q];
            for (int off = 32; off; off >>= 1) {
                a += __shfl_down(a, off);
                b2 += __shfl_down(b2, off);
            }
            if ((t & 63) == 0) { red[wv][k0 + q] = a; red[wv][32 + k0 + q] = b2; }
        }
    }
    __syncthreads();
    if (t < 96) {
        float s4 = red[0][t] + red[1][t] + red[2][t] + red[3][t];
        if (t < 64) {
            ws[OFF_HF + (long)row * 64 + t] = s4;    // [k]=cos-sum, [32+k]=sin-sum
        } else {
            red[0][t] = s4 * (1.0f / 2048.0f);       // scaled Cheb coeff, kept in LDS
        }
    }
    __syncthreads();
    // ---- rec = tanh(C . wbar) (fused k_b1) ----
    if (t < 4) {
        const float* wb = ws + OFF_WBAR + ((layer * 4 + t) * 8) * 128 + (row & 127);
        float a = 0.0f;
        #pragma unroll
        for (int mI = 0; mI < 8; mI++) a = fmaf(red[0][64 + t * 8 + mI], wb[mI * 128], a);
        ws[OFF_REC + (long)row * 4 + t] = tanhf(a);
    }
}

// ---------------- B2: mode mix -> omT (k-major); cgate; reset minmax ----------------
__global__ void k_b2(float* ws, const float* __restrict__ swr, const float* __restrict__ swi,
                     const float* __restrict__ gw, const float* __restrict__ gb, int layer) {
    int tid = blockIdx.x * 256 + threadIdx.x;
    if (tid < 32768) {
        int b = tid >> 12, o = (tid >> 5) & 127, k = tid & 31;
        const float* hfb = ws + OFF_HF + (long)b * 8192;  // [128][64]
        const float* wr = swr + (long)layer * 524288 + (long)o * 32 + k;
        const float* wi = swi + (long)layer * 524288 + (long)o * 32 + k;
        float omr = 0.0f, omi = 0.0f;
        for (int i = 0; i < 128; i++) {
            float hr = hfb[i * 64 + k];
            float hs = hfb[i * 64 + 32 + k];
            float wrv = wr[(long)i * 4096], wiv = wi[(long)i * 4096];
            omr = fmaf(hr, wrv, fmaf(hs, wiv, omr));
            omi = fmaf(hr, wiv, fmaf(-hs, wrv, omi));
        }
        float ck = (k == 0) ? (1.0f / 8192.0f) : (2.0f / 8192.0f);
        ws[OFF_OMCT + ((long)b * 32 + k) * 128 + o] = ck * omr;
        ws[OFF_OMST + ((long)b * 32 + k) * 128 + o] = -ck * omi;
    } else if (tid < 32768 + 4096) {
        int r = tid - 32768;
        int b = r >> 9, s = (r >> 7) & 3, o = r & 127;
        float a = gb[layer * 128 + o];
        const float* recp = ws + OFF_REC + (long)b * 512 + s;
        const float* g2 = gw + (long)layer * 32768 + 16384 + o;
        for (int c = 0; c < 128; c++) a = fmaf(recp[c * 4], g2[c * 128], a);
        ws[OFF_CG + (long)(b * 4 + s) * 128 + o] = a;
    }
    if (blockIdx.x == gridDim.x - 1 && threadIdx.x < 8) {
        unsigned int* mm = (unsigned int*)(ws + OFF_MNMX);
        mm[threadIdx.x] = (threadIdx.x < 4) ? 0xFFFFFFFFu : 0u;
    }
}

// ---------------- fused layer: irfft + conv + gelu + gate + update (in place) ----------------
// 256 threads, 8ch x 4pos per thread; VGPR cap 128 (4 waves/SIMD, LDS caps at 4 blocks/CU).
// All GEMM loops batched: 12 float4 loads issued together, then 128 FMAs -> deep ILP
// to cover the ~200cy L2 latency of weight reads (working set > L1).
__global__ __launch_bounds__(256, 4) void k_fuse(float* ws, const float* __restrict__ cw,
                                                 const float* __restrict__ cb,
                                                 const float* __restrict__ gw, int layer) {
    __shared__ float hx[128 * 68];
    __shared__ float rmn[4], rmx[4];
    int bid = blockIdx.x;
    int b = bid >> 7;
    int tile = bid & 127;
    int l0 = tile * 64;
    int seg = l0 >> 11;
    int t = threadIdx.x;
    float* hb = ws + OFF_H + (long)b * 1048576;

    #pragma unroll
    for (int i = 0; i < 8; i++) {
        int idx = t + i * 256;
        int row = idx >> 4, c4 = (idx & 15) * 4;
        *(float4*)&hx[row * 68 + c4] = *(const float4*)&hb[(long)row * 8192 + l0 + c4];
    }
    __syncthreads();

    int g = t >> 4, m = t & 15;
    int c0 = g * 8, p0 = m * 4;
    float acc[8][4] = {};

    // ---- inverse DFT (32 modes), k batched by 2: 12 float4 loads / 128 FMAs ----
    const float* btc = ws + OFF_BASTC + l0 + p0;
    const float* bts = ws + OFF_BASTS + l0 + p0;
    const float* omc = ws + OFF_OMCT + (long)b * 4096 + c0;
    const float* oms = ws + OFF_OMST + (long)b * 4096 + c0;
    for (int k = 0; k < 32; k += 2) {
        float4 bc0 = *(const float4*)&btc[k * 8192];
        float4 bs0 = *(const float4*)&bts[k * 8192];
        float4 oc00 = *(const float4*)&omc[k * 128];
        float4 oc01 = *(const float4*)&omc[k * 128 + 4];
        float4 os00 = *(const float4*)&oms[k * 128];
        float4 os01 = *(const float4*)&oms[k * 128 + 4];
        float4 bc1 = *(const float4*)&btc[(k + 1) * 8192];
        float4 bs1 = *(const float4*)&bts[(k + 1) * 8192];
        float4 oc10 = *(const float4*)&omc[(k + 1) * 128];
        float4 oc11 = *(const float4*)&omc[(k + 1) * 128 + 4];
        float4 os10 = *(const float4*)&oms[(k + 1) * 128];
        float4 os11 = *(const float4*)&oms[(k + 1) * 128 + 4];
        {
            float cv[4] = {bc0.x, bc0.y, bc0.z, bc0.w};
            float sv[4] = {bs0.x, bs0.y, bs0.z, bs0.w};
            float oc[8] = {oc00.x, oc00.y, oc00.z, oc00.w, oc01.x, oc01.y, oc01.z, oc01.w};
            float os[8] = {os00.x, os00.y, os00.z, os00.w, os01.x, os01.y, os01.z, os01.w};
            #pragma unroll
            for (int i = 0; i < 8; i++)
                #pragma unroll
                for (int p = 0; p < 4; p++)
                    acc[i][p] = fmaf(oc[i], cv[p], fmaf(os[i], sv[p], acc[i][p]));
        }
        {
            float cv[4] = {bc1.x, bc1.y, bc1.z, bc1.w};
            float sv[4] = {bs1.x, bs1.y, bs1.z, bs1.w};
            float oc[8] = {oc10.x, oc10.y, oc10.z, oc10.w, oc11.x, oc11.y, oc11.z, oc11.w};
            float os[8] = {os10.x, os10.y, os10.z, os10.w, os11.x, os11.y, os11.z, os11.w};
            #pragma unroll
            for (int i = 0; i < 8; i++)
                #pragma unroll
                for (int p = 0; p < 4; p++)
                    acc[i][p] = fmaf(oc[i], cv[p], fmaf(os[i], sv[p], acc[i][p]));
        }
    }
    // ---- 1x1 conv bypass, j batched by 4: 12 float4 loads / 128 FMAs ----
    const float* cwt = cw + (long)layer * 16384 + c0;
    for (int j = 0; j < 128; j += 4) {
        float4 hv[4], wA[4], wB[4];
        #pragma unroll
        for (int u = 0; u < 4; u++) {
            hv[u] = *(const float4*)&hx[(j + u) * 68 + p0];
            wA[u] = *(const float4*)&cwt[(j + u) * 128];
            wB[u] = *(const float4*)&cwt[(j + u) * 128 + 4];
        }
        #pragma unroll
        for (int u = 0; u < 4; u++) {
            float hvv[4] = {hv[u].x, hv[u].y, hv[u].z, hv[u].w};
            float wv[8] = {wA[u].x, wA[u].y, wA[u].z, wA[u].w,
                           wB[u].x, wB[u].y, wB[u].z, wB[u].w};
            #pragma unroll
            for (int i = 0; i < 8; i++)
                #pragma unroll
                for (int p = 0; p < 4; p++)
                    acc[i][p] = fmaf(hvv[p], wv[i], acc[i][p]);
        }
    }
    // bias + gelu; publish x_fno to LDS (h tile dead); do NOT keep in regs
    __syncthreads();   // all conv reads of h done
    #pragma unroll
    for (int i = 0; i < 8; i++) {
        float bias = cb[layer * 128 + c0 + i];
        float v0 = gelu_f(acc[i][0] + bias);
        float v1 = gelu_f(acc[i][1] + bias);
        float v2 = gelu_f(acc[i][2] + bias);
        float v3 = gelu_f(acc[i][3] + bias);
        *(float4*)&hx[(c0 + i) * 68 + p0] = make_float4(v0, v1, v2, v3);
    }
    __syncthreads();

    // ---- gate GEMM over x_fno, batched by 4 ----
    const float* gwl = gw + (long)layer * 32768 + c0;
    float gac[8][4] = {};
    for (int j = 0; j < 128; j += 4) {
        float4 xv[4], wA[4], wB[4];
        #pragma unroll
        for (int u = 0; u < 4; u++) {
            xv[u] = *(const float4*)&hx[(j + u) * 68 + p0];
            wA[u] = *(const float4*)&gwl[(j + u) * 128];
            wB[u] = *(const float4*)&gwl[(j + u) * 128 + 4];
        }
        #pragma unroll
        for (int u = 0; u < 4; u++) {
            float xvv[4] = {xv[u].x, xv[u].y, xv[u].z, xv[u].w};
            float wv[8] = {wA[u].x, wA[u].y, wA[u].z, wA[u].w,
                           wB[u].x, wB[u].y, wB[u].z, wB[u].w};
            #pragma unroll
            for (int i = 0; i < 8; i++)
                #pragma unroll
                for (int p = 0; p < 4; p++)
                    gac[i][p] = fmaf(xvv[p], wv[i], gac[i][p]);
        }
    }
    // epilogue: sigmoid gate, h update, seg min/max (x_fno re-read from LDS)
    float mnv = 1e30f, mxv = -1e30f;
    const float* cg = ws + OFF_CG + (long)(b * 4 + seg) * 128 + c0;
    #pragma unroll
    for (int i = 0; i < 8; i++) {
        float cgv = cg[i];
        float rv = ws[OFF_REC + (long)(b * 128 + c0 + i) * 4 + seg];
        float4 xf = *(const float4*)&hx[(c0 + i) * 68 + p0];
        float xfv[4] = {xf.x, xf.y, xf.z, xf.w};
        float v[4];
        #pragma unroll
        for (int p = 0; p < 4; p++) {
            float gg = sigmoid_f(gac[i][p] + cgv);
            v[p] = xfv[p] + gg * rv;
            mnv = fminf(mnv, v[p]); mxv = fmaxf(mxv, v[p]);
        }
        *(float4*)&hb[(long)(c0 + i) * 8192 + l0 + p0] = make_float4(v[0], v[1], v[2], v[3]);
    }
    for (int off = 32; off; off >>= 1) {
        mnv = fminf(mnv, __shfl_down(mnv, off));
        mxv = fmaxf(mxv, __shfl_down(mxv, off));
    }
    if ((t & 63) == 0) { rmn[t >> 6] = mnv; rmx[t >> 6] = mxv; }
    __syncthreads();
    if (t == 0) {
        for (int w2 = 1; w2 < 4; w2++) { mnv = fminf(mnv, rmn[w2]); mxv = fmaxf(mxv, rmx[w2]); }
        unsigned int* mm = (unsigned int*)(ws + OFF_MNMX);
        atomicMin(&mm[seg], enc_f(mnv));
        atomicMax(&mm[4 + seg], enc_f(mxv));
    }
}

// ---------------- final fc1(gelu) + fc2 (256 threads, batched loads) ----------------
__global__ __launch_bounds__(256, 4) void k_fc12(float* ws, const float* __restrict__ f1w,
                                                 const float* __restrict__ f1b,
                                                 const float* __restrict__ f2w,
                                                 const float* __restrict__ f2b,
                                                 float* __restrict__ out) {
    __shared__ float hx[128 * 68];
    int bid = blockIdx.x;
    int b = bid >> 7;
    int l0 = (bid & 127) * 64;
    int t = threadIdx.x;
    const float* hb = ws + OFF_H + (long)b * 1048576;
    #pragma unroll
    for (int i = 0; i < 8; i++) {
        int idx = t + i * 256;
        int row = idx >> 4, c4 = (idx & 15) * 4;
        *(float4*)&hx[row * 68 + c4] = *(const float4*)&hb[(long)row * 8192 + l0 + c4];
    }
    __syncthreads();
    int g = t >> 4, m = t & 15;
    int h0 = g * 8, p0 = m * 4;
    float acc[8][4] = {};
    const float* f1 = f1w + h0;
    for (int j = 0; j < 128; j += 4) {
        float4 hv[4], wA[4], wB[4];
        #pragma unroll
        for (int u = 0; u < 4; u++) {
            hv[u] = *(const float4*)&hx[(j + u) * 68 + p0];
            wA[u] = *(const float4*)&f1[(j + u) * 128];
            wB[u] = *(const float4*)&f1[(j + u) * 128 + 4];
        }
        #pragma unroll
        for (int u = 0; u < 4; u++) {
            float hvv[4] = {hv[u].x, hv[u].y, hv[u].z, hv[u].w};
            float wv[8] = {wA[u].x, wA[u].y, wA[u].z, wA[u].w,
                           wB[u].x, wB[u].y, wB[u].z, wB[u].w};
            #pragma unroll
            for (int i = 0; i < 8; i++)
                #pragma unroll
                for (int p = 0; p < 4; p++)
                    acc[i][p] = fmaf(hvv[p], wv[i], acc[i][p]);
        }
    }
    float outp[4] = {};
    #pragma unroll
    for (int i = 0; i < 8; i++) {
        float bias = f1b[h0 + i];
        float fw = f2w[h0 + i];
        #pragma unroll
        for (int p = 0; p < 4; p++)
            outp[p] = fmaf(fw, gelu_f(acc[i][p] + bias), outp[p]);
    }
    __syncthreads();   // done reading hx; reuse as reduction buffer [16 g][68]
    *(float4*)&hx[g * 68 + p0] = make_float4(outp[0], outp[1], outp[2], outp[3]);
    __syncthreads();
    if (t < 64) {
        float s = f2b[0];
        #pragma unroll
        for (int gg = 0; gg < 16; gg++) s += hx[gg * 68 + t];
        out[(long)b * 8192 + l0 + t] = s;
    }
}

extern "C" void kernel_launch(void* const* d_in, const int* in_sizes, int n_in,
                              void* d_out, int out_size, void* d_ws, size_t ws_size,
                              hipStream_t stream) {
    const float* x     = (const float*)d_in[0];
    const float* fc0_w = (const float*)d_in[1];
    const float* fc0_b = (const float*)d_in[2];
    const float* swr   = (const float*)d_in[3];
    const float* swi   = (const float*)d_in[4];
    const float* cw    = (const float*)d_in[5];
    const float* cb    = (const float*)d_in[6];
    const float* chw   = (const float*)d_in[7];
    const float* gw    = (const float*)d_in[8];
    const float* gb    = (const float*)d_in[9];
    const float* f1w   = (const float*)d_in[10];
    const float* f1b   = (const float*)d_in[11];
    const float* f2w   = (const float*)d_in[12];
    const float* f2b   = (const float*)d_in[13];
    float* ws = (float*)d_ws;
    float* out = (float*)d_out;

    k_tab<<<32, 256, 0, stream>>>(ws);
    k_init2<<<2112, 256, 0, stream>>>(ws, chw);
    k_fc0<<<256, 256, 0, stream>>>(ws, x, fc0_w, fc0_b);
    for (int layer = 0; layer < 4; layer++) {
        k_dftcb<<<1024, 256, 0, stream>>>(ws, layer);
        k_b2<<<144, 256, 0, stream>>>(ws, swr, swi, gw, gb, layer);
        k_fuse<<<1024, 256, 0, stream>>>(ws, cw, cb, gw, layer);
    }
    k_fc12<<<1024, 256, 0, stream>>>(ws, f1w, f1b, f2w, f2b, out);
}

// Round 3
// 690.512 us; speedup vs baseline: 1.1424x; 1.0937x over previous
//
#include <hip/hip_runtime.h>
#include <math.h>

// B=8, L=8192, W=128, MODES=32, NL=4, SEG=4 (seglen 2048), CM=8, H1=128

// ---------------- workspace layout (in floats) ----------------
#define OFF_COSTAB 0
#define OFF_SINTAB 8192
#define OFF_BASTC  16384                     // [32][8192]  cos(2*pi*k*l/L)
#define OFF_BASTS  (OFF_BASTC + 262144)      // [32][8192]  sin  (contiguous -> [64][8192])
#define OFF_UNUSED (OFF_BASTS + 262144)
#define OFF_WBAR   (OFF_UNUSED + 65536)      // [NL][SEG][CM][W]
#define OFF_HFP    (OFF_WBAR + 16384)        // (unused now)
#define OFF_HF     (OFF_HFP + 1048576)       // [1024][64]
#define OFF_CH     (OFF_HF + 65536)          // (unused now; rec fused)
#define OFF_REC    (OFF_CH + 32768)          // [8*128][4]
#define OFF_OMCT   (OFF_REC + 4096)          // [8][32 k][128 o]
#define OFF_OMST   (OFF_OMCT + 32768)        // [8][32 k][128 o]
#define OFF_CG     (OFF_OMST + 32768)        // [8][4][128]
#define OFF_MNMX   (OFF_CG + 4096)           // 8 uints
#define OFF_H      (OFF_MNMX + 16)           // [8][128][8192]

__device__ __forceinline__ unsigned int enc_f(float f) {
    unsigned int u = __float_as_uint(f);
    return (u & 0x80000000u) ? ~u : (u | 0x80000000u);
}
__device__ __forceinline__ float dec_f(unsigned int u) {
    return (u & 0x80000000u) ? __uint_as_float(u ^ 0x80000000u) : __uint_as_float(~u);
}
__device__ __forceinline__ float gelu_f(float x) {
    return 0.5f * x * (1.0f + erff(x * 0.70710678118654752f));
}
__device__ __forceinline__ float sigmoid_f(float x) {
    return 1.0f / (1.0f + expf(-x));
}

// cos/sin(2*pi*m/32) compile-time tables (fold to literals in unrolled FMAs)
constexpr float C32T[32] = {
    1.0f,          0.980785280f,  0.923879533f,  0.831469612f,
    0.707106781f,  0.555570233f,  0.382683432f,  0.195090322f,
    0.0f,         -0.195090322f, -0.382683432f, -0.555570233f,
   -0.707106781f, -0.831469612f, -0.923879533f, -0.980785280f,
   -1.0f,         -0.980785280f, -0.923879533f, -0.831469612f,
   -0.707106781f, -0.555570233f, -0.382683432f, -0.195090322f,
    0.0f,          0.195090322f,  0.382683432f,  0.555570233f,
    0.707106781f,  0.831469612f,  0.923879533f,  0.980785280f};
constexpr float S32T[32] = {
    0.0f,          0.195090322f,  0.382683432f,  0.555570233f,
    0.707106781f,  0.831469612f,  0.923879533f,  0.980785280f,
    1.0f,          0.980785280f,  0.923879533f,  0.831469612f,
    0.707106781f,  0.555570233f,  0.382683432f,  0.195090322f,
    0.0f,         -0.195090322f, -0.382683432f, -0.555570233f,
   -0.707106781f, -0.831469612f, -0.923879533f, -0.980785280f,
   -1.0f,         -0.980785280f, -0.923879533f, -0.831469612f,
   -0.707106781f, -0.555570233f, -0.382683432f, -0.195090322f};

// ---------------- init ----------------
__global__ void k_tab(float* ws) {
    int m = blockIdx.x * 256 + threadIdx.x;
    if (m < 8192) {
        double a = (double)m * (6.283185307179586476925286766559 / 8192.0);
        ws[OFF_COSTAB + m] = (float)cos(a);
        ws[OFF_SINTAB + m] = (float)sin(a);
    }
}

__global__ void k_init2(float* ws, const float* __restrict__ cheb_w) {
    int tid = blockIdx.x * 256 + threadIdx.x;
    if (tid < 524288) {
        int j = tid >> 13, l = tid & 8191;
        int k = j & 31;
        int tab = (j < 32) ? OFF_COSTAB : OFF_SINTAB;
        ws[OFF_BASTC + tid] = ws[tab + ((k * l) & 8191)];
    } else if (tid < 524288 + 16384) {
        int r = tid - 524288;           // ((layer*4+s)*8+m)*128 + c
        int c = r & 127;
        int smi = r >> 7;
        const float* wp = cheb_w + ((long)smi * 128 + c) * 128;
        float s = 0.0f;
        for (int o = 0; o < 128; o++) s += wp[o];
        ws[OFF_WBAR + r] = s * (1.0f / 128.0f);
    } else if (tid < 524288 + 16384 + 8) {
        int r = tid - (524288 + 16384);
        unsigned int* mm = (unsigned int*)(ws + OFF_MNMX);
        mm[r] = (r < 4) ? 0xFFFFFFFFu : 0u;
    }
}

// ---------------- fc0 + seg min/max ----------------
__global__ __launch_bounds__(256) void k_fc0(float* ws, const float* __restrict__ x,
                                             const float* __restrict__ w,
                                             const float* __restrict__ bias) {
    int bid = blockIdx.x;
    int b = bid >> 5;
    int l0 = (bid & 31) * 256;
    int t = threadIdx.x;
    int l = l0 + t;
    float x0 = x[((long)b * 8192 + l) * 2];
    float x1 = x[((long)b * 8192 + l) * 2 + 1];
    float* hb = ws + OFF_H + (long)b * 128 * 8192;
    float mn = 1e30f, mx = -1e30f;
    for (int c = 0; c < 128; c++) {
        float v = fmaf(x0, w[c], fmaf(x1, w[128 + c], bias[c]));
        hb[(long)c * 8192 + l] = v;
        mn = fminf(mn, v); mx = fmaxf(mx, v);
    }
    for (int off = 32; off; off >>= 1) {
        mn = fminf(mn, __shfl_down(mn, off));
        mx = fmaxf(mx, __shfl_down(mx, off));
    }
    __shared__ float rmn[4], rmx[4];
    if ((t & 63) == 0) { rmn[t >> 6] = mn; rmx[t >> 6] = mx; }
    __syncthreads();
    if (t == 0) {
        for (int w2 = 1; w2 < 4; w2++) { mn = fminf(mn, rmn[w2]); mx = fmaxf(mx, rmx[w2]); }
        unsigned int* mm = (unsigned int*)(ws + OFF_MNMX);
        int seg = l0 >> 11;
        atomicMin(&mm[seg], enc_f(mn));
        atomicMax(&mm[4 + seg], enc_f(mx));
    }
}

// ---------------- fused DFT(32 modes) + Chebyshev coeffs + rec ----------------
__global__ __launch_bounds__(256, 4) void k_dftcb(float* ws, int layer) {
    int row = blockIdx.x;              // b*128 + c
    int t = threadIdx.x;               // r = 0..255
    const float* hr = ws + OFF_H + (long)row * 8192;
    __shared__ float red[4][96];
    int wv = t >> 6;

    float ha[32];
    #pragma unroll
    for (int a = 0; a < 32; a++) ha[a] = hr[a * 256 + t];

    // ---- Chebyshev coefficients (fused k_cheb); seg of l=256a+t is a>>3 ----
    const unsigned int* mm = (const unsigned int*)(ws + OFF_MNMX);
    #pragma unroll
    for (int s = 0; s < 4; s++) {
        float mn = dec_f(mm[s]), mx = dec_f(mm[4 + s]);
        float sc = 2.0f / (mx - mn);
        float acc[8] = {};
        #pragma unroll
        for (int e = 0; e < 8; e++) {
            float xn = (ha[s * 8 + e] - mn) * sc - 1.0f;
            float tpp = 1.0f, tp = xn;
            acc[0] += xn;
            acc[1] += xn * xn;
            #pragma unroll
            for (int mI = 2; mI < 8; mI++) {
                float tn = 2.0f * xn * tp - tpp;
                acc[mI] += xn * tn;
                tpp = tp; tp = tn;
            }
        }
        #pragma unroll
        for (int mI = 0; mI < 8; mI++) {
            float v = acc[mI];
            for (int off = 32; off; off >>= 1) v += __shfl_down(v, off);
            if ((t & 63) == 0) red[wv][64 + s * 8 + mI] = v;
        }
    }

    // ---- inner 32-point real DFT over a, folded a<->32-a ----
    float ep[16], em[16];
    #pragma unroll
    for (int a = 1; a < 16; a++) { ep[a] = ha[a] + ha[32 - a]; em[a] = ha[a] - ha[32 - a]; }
    float h0 = ha[0], h16 = ha[16];
    float Ca[17], Sa[17];
    #pragma unroll
    for (int k = 0; k <= 16; k++) {
        float ca = (k & 1) ? (h0 - h16) : (h0 + h16);
        float sa = 0.0f;
        #pragma unroll
        for (int a = 1; a < 16; a++) {
            ca = fmaf(ep[a], C32T[(k * a) & 31], ca);
            sa = fmaf(em[a], S32T[(k * a) & 31], sa);
        }
        Ca[k] = ca; Sa[k] = sa;
    }
    // Hermitian: Ca[32-k]=Ca[k], Sa[32-k]=-Sa[k]

    // ---- twiddle by theta = 2*pi*k*t/8192 and block-reduce ----
    const float* ct = ws + OFF_COSTAB;
    const float* st = ws + OFF_SINTAB;
    #pragma unroll
    for (int k0 = 0; k0 < 32; k0 += 8) {
        float xr[8], xi[8];
        #pragma unroll
        for (int q = 0; q < 8; q++) {
            int k = k0 + q;
            float caf = (k <= 16) ? Ca[k] : Ca[32 - k];
            float saf = (k <= 16) ? Sa[k] : -Sa[32 - k];
            float c = ct[(k * t) & 8191];
            float s = st[(k * t) & 8191];
            xr[q] = caf * c - saf * s;               // partial of sum h*cos
            xi[q] = fmaf(saf, c, caf * s);           // partial of sum h*sin
        }
        #pragma unroll
        for (int q = 0; q < 8; q++) {
            float a = xr[q], b2 = xi[q];
            for (int off = 32; off; off >>= 1) {
                a += __shfl_down(a, off);
                b2 += __shfl_down(b2, off);
            }
            if ((t & 63) == 0) { red[wv][k0 + q] = a; red[wv][32 + k0 + q] = b2; }
        }
    }
    __syncthreads();
    if (t < 96) {
        float s4 = red[0][t] + red[1][t] + red[2][t] + red[3][t];
        if (t < 64) {
            ws[OFF_HF + (long)row * 64 + t] = s4;    // [k]=cos-sum, [32+k]=sin-sum
        } else {
            red[0][t] = s4 * (1.0f / 2048.0f);       // scaled Cheb coeff, kept in LDS
        }
    }
    __syncthreads();
    // ---- rec = tanh(C . wbar) (fused k_b1) ----
    if (t < 4) {
        const float* wb = ws + OFF_WBAR + ((layer * 4 + t) * 8) * 128 + (row & 127);
        float a = 0.0f;
        #pragma unroll
        for (int mI = 0; mI < 8; mI++) a = fmaf(red[0][64 + t * 8 + mI], wb[mI * 128], a);
        ws[OFF_REC + (long)row * 4 + t] = tanhf(a);
    }
}

// ---------------- B2: mode mix -> omT (k-major); cgate; reset minmax ----------------
__global__ void k_b2(float* ws, const float* __restrict__ swr, const float* __restrict__ swi,
                     const float* __restrict__ gw, const float* __restrict__ gb, int layer) {
    int tid = blockIdx.x * 256 + threadIdx.x;
    if (tid < 32768) {
        int b = tid >> 12, o = (tid >> 5) & 127, k = tid & 31;
        const float* hfb = ws + OFF_HF + (long)b * 8192;  // [128][64]
        const float* wr = swr + (long)layer * 524288 + (long)o * 32 + k;
        const float* wi = swi + (long)layer * 524288 + (long)o * 32 + k;
        float omr = 0.0f, omi = 0.0f;
        for (int i = 0; i < 128; i++) {
            float hr = hfb[i * 64 + k];
            float hs = hfb[i * 64 + 32 + k];
            float wrv = wr[(long)i * 4096], wiv = wi[(long)i * 4096];
            omr = fmaf(hr, wrv, fmaf(hs, wiv, omr));
            omi = fmaf(hr, wiv, fmaf(-hs, wrv, omi));
        }
        float ck = (k == 0) ? (1.0f / 8192.0f) : (2.0f / 8192.0f);
        ws[OFF_OMCT + ((long)b * 32 + k) * 128 + o] = ck * omr;
        ws[OFF_OMST + ((long)b * 32 + k) * 128 + o] = -ck * omi;
    } else if (tid < 32768 + 4096) {
        int r = tid - 32768;
        int b = r >> 9, s = (r >> 7) & 3, o = r & 127;
        float a = gb[layer * 128 + o];
        const float* recp = ws + OFF_REC + (long)b * 512 + s;
        const float* g2 = gw + (long)layer * 32768 + 16384 + o;
        for (int c = 0; c < 128; c++) a = fmaf(recp[c * 4], g2[c * 128], a);
        ws[OFF_CG + (long)(b * 4 + s) * 128 + o] = a;
    }
    if (blockIdx.x == gridDim.x - 1 && threadIdx.x < 8) {
        unsigned int* mm = (unsigned int*)(ws + OFF_MNMX);
        mm[threadIdx.x] = (threadIdx.x < 4) ? 0xFFFFFFFFu : 0u;
    }
}

// ---------------- fused layer: irfft + conv + gelu + gate + update (in place) ----------------
// Wave-uniform weight addressing: wave -> 32 output channels, lane -> 1 position.
// All weight reads (om, cw, gw, rec, cg, cb) are wave-uniform -> scalar (s_load) pipe;
// per-lane traffic is 2 global loads per k and 1 conflict-free ds_read_b32 per j.
// Separate __restrict__ region pointers so the backend can prove no-alias and scalarize.
__global__ __launch_bounds__(256, 4) void k_fuse(
    float* __restrict__ hglob,            // ws + OFF_H
    const float* __restrict__ basc,       // ws + OFF_BASTC
    const float* __restrict__ bass,       // ws + OFF_BASTS
    const float* __restrict__ omct,       // ws + OFF_OMCT
    const float* __restrict__ omst,       // ws + OFF_OMST
    const float* __restrict__ rec,        // ws + OFF_REC
    const float* __restrict__ cgt,        // ws + OFF_CG
    unsigned int* __restrict__ mnmx,      // ws + OFF_MNMX
    const float* __restrict__ cw, const float* __restrict__ cb,
    const float* __restrict__ gw, int layer) {
    __shared__ float hx[128 * 64];
    __shared__ float rmn[4], rmx[4];
    int bid = blockIdx.x;
    int b = bid >> 7;
    int l0 = (bid & 127) * 64;
    int seg = l0 >> 11;
    int t = threadIdx.x;
    float* hb = hglob + (long)b * 1048576;

    // stage h tile [128 ch][64 pos] (stride 64: lane-consecutive reads are conflict-free)
    #pragma unroll
    for (int i = 0; i < 8; i++) {
        int idx = t + i * 256;
        int row = idx >> 4, c4 = (idx & 15) * 4;
        *(float4*)&hx[row * 64 + c4] = *(const float4*)&hb[(long)row * 8192 + l0 + c4];
    }
    __syncthreads();

    int p = t & 63;                                        // lane = position
    int c0 = __builtin_amdgcn_readfirstlane((t >> 6) * 32); // wave's channel base

    float acc[32] = {};

    // ---- inverse DFT (32 modes): 2 coalesced lane loads + 64 scalar weights per k ----
    const float* btp = basc + l0 + p;
    const float* bsp = bass + l0 + p;
    const float* omc = omct + (long)b * 4096 + c0;
    const float* oms = omst + (long)b * 4096 + c0;
    #pragma unroll 2
    for (int k = 0; k < 32; k++) {
        float bcv = btp[k * 8192];
        float bsv = bsp[k * 8192];
        #pragma unroll
        for (int c = 0; c < 32; c++)
            acc[c] = fmaf(omc[k * 128 + c], bcv, fmaf(oms[k * 128 + c], bsv, acc[c]));
    }
    // ---- 1x1 conv bypass: 1 ds_read_b32 + 32 scalar weights per j ----
    const float* cwt = cw + (long)layer * 16384 + c0;
    #pragma unroll 2
    for (int j = 0; j < 128; j++) {
        float hv = hx[j * 64 + p];
        #pragma unroll
        for (int c = 0; c < 32; c++)
            acc[c] = fmaf(cwt[j * 128 + c], hv, acc[c]);
    }
    // bias + gelu -> x_fno kept in regs
    const float* cbl = cb + layer * 128 + c0;
    #pragma unroll
    for (int c = 0; c < 32; c++) acc[c] = gelu_f(acc[c] + cbl[c]);
    __syncthreads();   // all conv reads of h done
    #pragma unroll
    for (int c = 0; c < 32; c++) hx[(c0 + c) * 64 + p] = acc[c];
    __syncthreads();

    // ---- gate GEMM over x_fno: same scalar-weight structure ----
    const float* gwl = gw + (long)layer * 32768 + c0;
    float gac[32] = {};
    #pragma unroll 2
    for (int j = 0; j < 128; j++) {
        float xv = hx[j * 64 + p];
        #pragma unroll
        for (int c = 0; c < 32; c++)
            gac[c] = fmaf(gwl[j * 128 + c], xv, gac[c]);
    }
    // epilogue: sigmoid gate, h update, seg min/max
    const float* cgp = cgt + (long)(b * 4 + seg) * 128 + c0;
    const float* rcp = rec + (long)(b * 128 + c0) * 4 + seg;
    float mnv = 1e30f, mxv = -1e30f;
    #pragma unroll
    for (int c = 0; c < 32; c++) {
        float gg = sigmoid_f(gac[c] + cgp[c]);
        float v = fmaf(gg, rcp[c * 4], acc[c]);
        mnv = fminf(mnv, v); mxv = fmaxf(mxv, v);
        hb[(long)(c0 + c) * 8192 + l0 + p] = v;
    }
    for (int off = 32; off; off >>= 1) {
        mnv = fminf(mnv, __shfl_down(mnv, off));
        mxv = fmaxf(mxv, __shfl_down(mxv, off));
    }
    if ((t & 63) == 0) { rmn[t >> 6] = mnv; rmx[t >> 6] = mxv; }
    __syncthreads();
    if (t == 0) {
        for (int w2 = 1; w2 < 4; w2++) { mnv = fminf(mnv, rmn[w2]); mxv = fmaxf(mxv, rmx[w2]); }
        atomicMin(&mnmx[seg], enc_f(mnv));
        atomicMax(&mnmx[4 + seg], enc_f(mxv));
    }
}

// ---------------- final fc1(gelu) + fc2: same wave-uniform scalar-weight structure ----
__global__ __launch_bounds__(256, 4) void k_fc12(
    const float* __restrict__ hglob, const float* __restrict__ f1w,
    const float* __restrict__ f1b, const float* __restrict__ f2w,
    const float* __restrict__ f2b, float* __restrict__ out) {
    __shared__ float hx[128 * 64];
    int bid = blockIdx.x;
    int b = bid >> 7;
    int l0 = (bid & 127) * 64;
    int t = threadIdx.x;
    const float* hb = hglob + (long)b * 1048576;
    #pragma unroll
    for (int i = 0; i < 8; i++) {
        int idx = t + i * 256;
        int row = idx >> 4, c4 = (idx & 15) * 4;
        *(float4*)&hx[row * 64 + c4] = *(const float4*)&hb[(long)row * 8192 + l0 + c4];
    }
    __syncthreads();
    int p = t & 63;
    int h0 = __builtin_amdgcn_readfirstlane((t >> 6) * 32);
    float acc[32] = {};
    const float* f1 = f1w + h0;
    #pragma unroll 2
    for (int j = 0; j < 128; j++) {
        float xv = hx[j * 64 + p];
        #pragma unroll
        for (int c = 0; c < 32; c++)
            acc[c] = fmaf(f1[j * 128 + c], xv, acc[c]);
    }
    float outp = 0.0f;
    #pragma unroll
    for (int c = 0; c < 32; c++)
        outp = fmaf(f2w[h0 + c], gelu_f(acc[c] + f1b[h0 + c]), outp);
    __syncthreads();   // done reading hx; reuse as wave-partial buffer [4][64]
    hx[(t >> 6) * 64 + p] = outp;
    __syncthreads();
    if (t < 64) {
        float s = f2b[0] + hx[t] + hx[64 + t] + hx[128 + t] + hx[192 + t];
        out[(long)b * 8192 + l0 + t] = s;
    }
}

extern "C" void kernel_launch(void* const* d_in, const int* in_sizes, int n_in,
                              void* d_out, int out_size, void* d_ws, size_t ws_size,
                              hipStream_t stream) {
    const float* x     = (const float*)d_in[0];
    const float* fc0_w = (const float*)d_in[1];
    const float* fc0_b = (const float*)d_in[2];
    const float* swr   = (const float*)d_in[3];
    const float* swi   = (const float*)d_in[4];
    const float* cw    = (const float*)d_in[5];
    const float* cb    = (const float*)d_in[6];
    const float* chw   = (const float*)d_in[7];
    const float* gw    = (const float*)d_in[8];
    const float* gb    = (const float*)d_in[9];
    const float* f1w   = (const float*)d_in[10];
    const float* f1b   = (const float*)d_in[11];
    const float* f2w   = (const float*)d_in[12];
    const float* f2b   = (const float*)d_in[13];
    float* ws = (float*)d_ws;
    float* out = (float*)d_out;

    k_tab<<<32, 256, 0, stream>>>(ws);
    k_init2<<<2112, 256, 0, stream>>>(ws, chw);
    k_fc0<<<256, 256, 0, stream>>>(ws, x, fc0_w, fc0_b);
    for (int layer = 0; layer < 4; layer++) {
        k_dftcb<<<1024, 256, 0, stream>>>(ws, layer);
        k_b2<<<144, 256, 0, stream>>>(ws, swr, swi, gw, gb, layer);
        k_fuse<<<1024, 256, 0, stream>>>(ws + OFF_H, ws + OFF_BASTC, ws + OFF_BASTS,
                                         ws + OFF_OMCT, ws + OFF_OMST, ws + OFF_REC,
                                         ws + OFF_CG, (unsigned int*)(ws + OFF_MNMX),
                                         cw, cb, gw, layer);
    }
    k_fc12<<<1024, 256, 0, stream>>>(ws + OFF_H, f1w, f1b, f2w, f2b, out);
}

// Round 4
// 647.658 us; speedup vs baseline: 1.2179x; 1.0662x over previous
//
#include <hip/hip_runtime.h>
#include <math.h>

// B=8, L=8192, W=128, MODES=32, NL=4, SEG=4 (seglen 2048), CM=8, H1=128

// ---------------- workspace layout (in floats) ----------------
#define OFF_COSTAB 0
#define OFF_SINTAB 8192
#define OFF_BASTC  16384                     // [32][8192]  cos(2*pi*k*l/L)
#define OFF_BASTS  (OFF_BASTC + 262144)      // [32][8192]  sin  (contiguous -> [64][8192])
#define OFF_UNUSED (OFF_BASTS + 262144)
#define OFF_WBAR   (OFF_UNUSED + 65536)      // [NL][SEG][CM][W]
#define OFF_HFP    (OFF_WBAR + 16384)        // (unused now)
#define OFF_HF     (OFF_HFP + 1048576)       // [1024][64]
#define OFF_CH     (OFF_HF + 65536)          // (unused now; rec fused)
#define OFF_REC    (OFF_CH + 32768)          // [8*128][4]
#define OFF_OMCT   (OFF_REC + 4096)          // [8][32 k][128 o]
#define OFF_OMST   (OFF_OMCT + 32768)        // [8][32 k][128 o]
#define OFF_CG     (OFF_OMST + 32768)        // [8][4][128]
#define OFF_MNMX   (OFF_CG + 4096)           // 8 uints
#define OFF_H      (OFF_MNMX + 16)           // [8][128][8192]

__device__ __forceinline__ unsigned int enc_f(float f) {
    unsigned int u = __float_as_uint(f);
    return (u & 0x80000000u) ? ~u : (u | 0x80000000u);
}
__device__ __forceinline__ float dec_f(unsigned int u) {
    return (u & 0x80000000u) ? __uint_as_float(u ^ 0x80000000u) : __uint_as_float(~u);
}
__device__ __forceinline__ float gelu_f(float x) {
    return 0.5f * x * (1.0f + erff(x * 0.70710678118654752f));
}
__device__ __forceinline__ float sigmoid_f(float x) {
    return 1.0f / (1.0f + expf(-x));
}

// cos/sin(2*pi*m/32) compile-time tables (fold to literals in unrolled FMAs)
constexpr float C32T[32] = {
    1.0f,          0.980785280f,  0.923879533f,  0.831469612f,
    0.707106781f,  0.555570233f,  0.382683432f,  0.195090322f,
    0.0f,         -0.195090322f, -0.382683432f, -0.555570233f,
   -0.707106781f, -0.831469612f, -0.923879533f, -0.980785280f,
   -1.0f,         -0.980785280f, -0.923879533f, -0.831469612f,
   -0.707106781f, -0.555570233f, -0.382683432f, -0.195090322f,
    0.0f,          0.195090322f,  0.382683432f,  0.555570233f,
    0.707106781f,  0.831469612f,  0.923879533f,  0.980785280f};
constexpr float S32T[32] = {
    0.0f,          0.195090322f,  0.382683432f,  0.555570233f,
    0.707106781f,  0.831469612f,  0.923879533f,  0.980785280f,
    1.0f,          0.980785280f,  0.923879533f,  0.831469612f,
    0.707106781f,  0.555570233f,  0.382683432f,  0.195090322f,
    0.0f,         -0.195090322f, -0.382683432f, -0.555570233f,
   -0.707106781f, -0.831469612f, -0.923879533f, -0.980785280f,
   -1.0f,         -0.980785280f, -0.923879533f, -0.831469612f,
   -0.707106781f, -0.555570233f, -0.382683432f, -0.195090322f};

// ---------------- init ----------------
__global__ void k_tab(float* ws) {
    int m = blockIdx.x * 256 + threadIdx.x;
    if (m < 8192) {
        double a = (double)m * (6.283185307179586476925286766559 / 8192.0);
        ws[OFF_COSTAB + m] = (float)cos(a);
        ws[OFF_SINTAB + m] = (float)sin(a);
    }
}

__global__ void k_init2(float* ws, const float* __restrict__ cheb_w) {
    int tid = blockIdx.x * 256 + threadIdx.x;
    if (tid < 524288) {
        int j = tid >> 13, l = tid & 8191;
        int k = j & 31;
        int tab = (j < 32) ? OFF_COSTAB : OFF_SINTAB;
        ws[OFF_BASTC + tid] = ws[tab + ((k * l) & 8191)];
    } else if (tid < 524288 + 16384) {
        int r = tid - 524288;           // ((layer*4+s)*8+m)*128 + c
        int c = r & 127;
        int smi = r >> 7;
        const float* wp = cheb_w + ((long)smi * 128 + c) * 128;
        float s = 0.0f;
        for (int o = 0; o < 128; o++) s += wp[o];
        ws[OFF_WBAR + r] = s * (1.0f / 128.0f);
    } else if (tid < 524288 + 16384 + 8) {
        int r = tid - (524288 + 16384);
        unsigned int* mm = (unsigned int*)(ws + OFF_MNMX);
        mm[r] = (r < 4) ? 0xFFFFFFFFu : 0u;
    }
}

// ---------------- fc0 + seg min/max ----------------
__global__ __launch_bounds__(256) void k_fc0(float* ws, const float* __restrict__ x,
                                             const float* __restrict__ w,
                                             const float* __restrict__ bias) {
    int bid = blockIdx.x;
    int b = bid >> 5;
    int l0 = (bid & 31) * 256;
    int t = threadIdx.x;
    int l = l0 + t;
    float x0 = x[((long)b * 8192 + l) * 2];
    float x1 = x[((long)b * 8192 + l) * 2 + 1];
    float* hb = ws + OFF_H + (long)b * 128 * 8192;
    float mn = 1e30f, mx = -1e30f;
    for (int c = 0; c < 128; c++) {
        float v = fmaf(x0, w[c], fmaf(x1, w[128 + c], bias[c]));
        hb[(long)c * 8192 + l] = v;
        mn = fminf(mn, v); mx = fmaxf(mx, v);
    }
    for (int off = 32; off; off >>= 1) {
        mn = fminf(mn, __shfl_down(mn, off));
        mx = fmaxf(mx, __shfl_down(mx, off));
    }
    __shared__ float rmn[4], rmx[4];
    if ((t & 63) == 0) { rmn[t >> 6] = mn; rmx[t >> 6] = mx; }
    __syncthreads();
    if (t == 0) {
        for (int w2 = 1; w2 < 4; w2++) { mn = fminf(mn, rmn[w2]); mx = fmaxf(mx, rmx[w2]); }
        unsigned int* mm = (unsigned int*)(ws + OFF_MNMX);
        int seg = l0 >> 11;
        atomicMin(&mm[seg], enc_f(mn));
        atomicMax(&mm[4 + seg], enc_f(mx));
    }
}

// ---------------- fused DFT(32 modes) + Chebyshev coeffs + rec ----------------
__global__ __launch_bounds__(256, 4) void k_dftcb(float* ws, int layer) {
    int row = blockIdx.x;              // b*128 + c
    int t = threadIdx.x;               // r = 0..255
    const float* hr = ws + OFF_H + (long)row * 8192;
    __shared__ float red[4][96];
    int wv = t >> 6;

    float ha[32];
    #pragma unroll
    for (int a = 0; a < 32; a++) ha[a] = hr[a * 256 + t];

    // ---- Chebyshev coefficients (fused k_cheb); seg of l=256a+t is a>>3 ----
    const unsigned int* mm = (const unsigned int*)(ws + OFF_MNMX);
    #pragma unroll
    for (int s = 0; s < 4; s++) {
        float mn = dec_f(mm[s]), mx = dec_f(mm[4 + s]);
        float sc = 2.0f / (mx - mn);
        float acc[8] = {};
        #pragma unroll
        for (int e = 0; e < 8; e++) {
            float xn = (ha[s * 8 + e] - mn) * sc - 1.0f;
            float tpp = 1.0f, tp = xn;
            acc[0] += xn;
            acc[1] += xn * xn;
            #pragma unroll
            for (int mI = 2; mI < 8; mI++) {
                float tn = 2.0f * xn * tp - tpp;
                acc[mI] += xn * tn;
                tpp = tp; tp = tn;
            }
        }
        #pragma unroll
        for (int mI = 0; mI < 8; mI++) {
            float v = acc[mI];
            for (int off = 32; off; off >>= 1) v += __shfl_down(v, off);
            if ((t & 63) == 0) red[wv][64 + s * 8 + mI] = v;
        }
    }

    // ---- inner 32-point real DFT over a, folded a<->32-a ----
    float ep[16], em[16];
    #pragma unroll
    for (int a = 1; a < 16; a++) { ep[a] = ha[a] + ha[32 - a]; em[a] = ha[a] - ha[32 - a]; }
    float h0 = ha[0], h16 = ha[16];
    float Ca[17], Sa[17];
    #pragma unroll
    for (int k = 0; k <= 16; k++) {
        float ca = (k & 1) ? (h0 - h16) : (h0 + h16);
        float sa = 0.0f;
        #pragma unroll
        for (int a = 1; a < 16; a++) {
            ca = fmaf(ep[a], C32T[(k * a) & 31], ca);
            sa = fmaf(em[a], S32T[(k * a) & 31], sa);
        }
        Ca[k] = ca; Sa[k] = sa;
    }
    // Hermitian: Ca[32-k]=Ca[k], Sa[32-k]=-Sa[k]

    // ---- twiddle by theta = 2*pi*k*t/8192 and block-reduce ----
    const float* ct = ws + OFF_COSTAB;
    const float* st = ws + OFF_SINTAB;
    #pragma unroll
    for (int k0 = 0; k0 < 32; k0 += 8) {
        float xr[8], xi[8];
        #pragma unroll
        for (int q = 0; q < 8; q++) {
            int k = k0 + q;
            float caf = (k <= 16) ? Ca[k] : Ca[32 - k];
            float saf = (k <= 16) ? Sa[k] : -Sa[32 - k];
            float c = ct[(k * t) & 8191];
            float s = st[(k * t) & 8191];
            xr[q] = caf * c - saf * s;               // partial of sum h*cos
            xi[q] = fmaf(saf, c, caf * s);           // partial of sum h*sin
        }
        #pragma unroll
        for (int q = 0; q < 8; q++) {
            float a = xr[q], b2 = xi[q];
            for (int off = 32; off; off >>= 1) {
                a += __shfl_down(a, off);
                b2 += __shfl_down(b2, off);
            }
            if ((t & 63) == 0) { red[wv][k0 + q] = a; red[wv][32 + k0 + q] = b2; }
        }
    }
    __syncthreads();
    if (t < 96) {
        float s4 = red[0][t] + red[1][t] + red[2][t] + red[3][t];
        if (t < 64) {
            ws[OFF_HF + (long)row * 64 + t] = s4;    // [k]=cos-sum, [32+k]=sin-sum
        } else {
            red[0][t] = s4 * (1.0f / 2048.0f);       // scaled Cheb coeff, kept in LDS
        }
    }
    __syncthreads();
    // ---- rec = tanh(C . wbar) (fused k_b1) ----
    if (t < 4) {
        const float* wb = ws + OFF_WBAR + ((layer * 4 + t) * 8) * 128 + (row & 127);
        float a = 0.0f;
        #pragma unroll
        for (int mI = 0; mI < 8; mI++) a = fmaf(red[0][64 + t * 8 + mI], wb[mI * 128], a);
        ws[OFF_REC + (long)row * 4 + t] = tanhf(a);
    }
}

// ---------------- B2: mode mix -> omT (k-major); cgate; reset minmax ----------------
__global__ void k_b2(float* ws, const float* __restrict__ swr, const float* __restrict__ swi,
                     const float* __restrict__ gw, const float* __restrict__ gb, int layer) {
    int tid = blockIdx.x * 256 + threadIdx.x;
    if (tid < 32768) {
        int b = tid >> 12, o = (tid >> 5) & 127, k = tid & 31;
        const float* hfb = ws + OFF_HF + (long)b * 8192;  // [128][64]
        const float* wr = swr + (long)layer * 524288 + (long)o * 32 + k;
        const float* wi = swi + (long)layer * 524288 + (long)o * 32 + k;
        float omr = 0.0f, omi = 0.0f;
        for (int i = 0; i < 128; i++) {
            float hr = hfb[i * 64 + k];
            float hs = hfb[i * 64 + 32 + k];
            float wrv = wr[(long)i * 4096], wiv = wi[(long)i * 4096];
            omr = fmaf(hr, wrv, fmaf(hs, wiv, omr));
            omi = fmaf(hr, wiv, fmaf(-hs, wrv, omi));
        }
        float ck = (k == 0) ? (1.0f / 8192.0f) : (2.0f / 8192.0f);
        ws[OFF_OMCT + ((long)b * 32 + k) * 128 + o] = ck * omr;
        ws[OFF_OMST + ((long)b * 32 + k) * 128 + o] = -ck * omi;
    } else if (tid < 32768 + 4096) {
        int r = tid - 32768;
        int b = r >> 9, s = (r >> 7) & 3, o = r & 127;
        float a = gb[layer * 128 + o];
        const float* recp = ws + OFF_REC + (long)b * 512 + s;
        const float* g2 = gw + (long)layer * 32768 + 16384 + o;
        for (int c = 0; c < 128; c++) a = fmaf(recp[c * 4], g2[c * 128], a);
        ws[OFF_CG + (long)(b * 4 + s) * 128 + o] = a;
    }
    if (blockIdx.x == gridDim.x - 1 && threadIdx.x < 8) {
        unsigned int* mm = (unsigned int*)(ws + OFF_MNMX);
        mm[threadIdx.x] = (threadIdx.x < 4) ? 0xFFFFFFFFu : 0u;
    }
}

// ---------------- fused layer: irfft + conv + gelu + gate + update (in place) ----------------
// Wave-uniform scalar weights (SGPR pipe) + 512 threads / 16 ch per wave:
// 4 blocks/CU x 8 waves = 32 waves/CU (HW cap) to hide s_load/ds_read latency.
// Per-output accumulation order identical to the 256-thread version.
__global__ __launch_bounds__(512, 8) void k_fuse(
    float* __restrict__ hglob,            // ws + OFF_H
    const float* __restrict__ basc,       // ws + OFF_BASTC
    const float* __restrict__ bass,       // ws + OFF_BASTS
    const float* __restrict__ omct,       // ws + OFF_OMCT
    const float* __restrict__ omst,       // ws + OFF_OMST
    const float* __restrict__ rec,        // ws + OFF_REC
    const float* __restrict__ cgt,        // ws + OFF_CG
    unsigned int* __restrict__ mnmx,      // ws + OFF_MNMX
    const float* __restrict__ cw, const float* __restrict__ cb,
    const float* __restrict__ gw, int layer) {
    __shared__ float hx[128 * 64];
    __shared__ float rmn[8], rmx[8];
    int bid = blockIdx.x;
    int b = bid >> 7;
    int l0 = (bid & 127) * 64;
    int seg = l0 >> 11;
    int t = threadIdx.x;
    float* hb = hglob + (long)b * 1048576;

    // stage h tile [128 ch][64 pos]
    #pragma unroll
    for (int i = 0; i < 4; i++) {
        int idx = t + i * 512;
        int row = idx >> 4, c4 = (idx & 15) * 4;
        *(float4*)&hx[row * 64 + c4] = *(const float4*)&hb[(long)row * 8192 + l0 + c4];
    }
    __syncthreads();

    int p = t & 63;                                         // lane = position
    int c0 = __builtin_amdgcn_readfirstlane((t >> 6) * 16); // wave's channel base

    float acc[16] = {};

    // ---- inverse DFT (32 modes): 2 coalesced lane loads + 32 scalar weights per k ----
    const float* btp = basc + l0 + p;
    const float* bsp = bass + l0 + p;
    const float* omc = omct + (long)b * 4096 + c0;
    const float* oms = omst + (long)b * 4096 + c0;
    #pragma unroll 2
    for (int k = 0; k < 32; k++) {
        float bcv = btp[k * 8192];
        float bsv = bsp[k * 8192];
        #pragma unroll
        for (int c = 0; c < 16; c++)
            acc[c] = fmaf(omc[k * 128 + c], bcv, fmaf(oms[k * 128 + c], bsv, acc[c]));
    }
    // ---- 1x1 conv bypass: 1 conflict-free ds_read_b32 + 16 scalar weights per j ----
    const float* cwt = cw + (long)layer * 16384 + c0;
    #pragma unroll 2
    for (int j = 0; j < 128; j++) {
        float hv = hx[j * 64 + p];
        #pragma unroll
        for (int c = 0; c < 16; c++)
            acc[c] = fmaf(cwt[j * 128 + c], hv, acc[c]);
    }
    // bias + gelu -> x_fno kept in regs
    const float* cbl = cb + layer * 128 + c0;
    #pragma unroll
    for (int c = 0; c < 16; c++) acc[c] = gelu_f(acc[c] + cbl[c]);
    __syncthreads();   // all conv reads of h done
    #pragma unroll
    for (int c = 0; c < 16; c++) hx[(c0 + c) * 64 + p] = acc[c];
    __syncthreads();

    // ---- gate GEMM over x_fno: same scalar-weight structure ----
    const float* gwl = gw + (long)layer * 32768 + c0;
    float gac[16] = {};
    #pragma unroll 2
    for (int j = 0; j < 128; j++) {
        float xv = hx[j * 64 + p];
        #pragma unroll
        for (int c = 0; c < 16; c++)
            gac[c] = fmaf(gwl[j * 128 + c], xv, gac[c]);
    }
    // epilogue: sigmoid gate, h update, seg min/max
    const float* cgp = cgt + (long)(b * 4 + seg) * 128 + c0;
    const float* rcp = rec + (long)(b * 128 + c0) * 4 + seg;
    float mnv = 1e30f, mxv = -1e30f;
    #pragma unroll
    for (int c = 0; c < 16; c++) {
        float gg = sigmoid_f(gac[c] + cgp[c]);
        float v = fmaf(gg, rcp[c * 4], acc[c]);
        mnv = fminf(mnv, v); mxv = fmaxf(mxv, v);
        hb[(long)(c0 + c) * 8192 + l0 + p] = v;
    }
    for (int off = 32; off; off >>= 1) {
        mnv = fminf(mnv, __shfl_down(mnv, off));
        mxv = fmaxf(mxv, __shfl_down(mxv, off));
    }
    if ((t & 63) == 0) { rmn[t >> 6] = mnv; rmx[t >> 6] = mxv; }
    __syncthreads();
    if (t == 0) {
        for (int w2 = 1; w2 < 8; w2++) { mnv = fminf(mnv, rmn[w2]); mxv = fmaxf(mxv, rmx[w2]); }
        atomicMin(&mnmx[seg], enc_f(mnv));
        atomicMax(&mnmx[4 + seg], enc_f(mxv));
    }
}

// ---------------- final fc1(gelu) + fc2: same 512-thread scalar-weight structure ----
__global__ __launch_bounds__(512, 8) void k_fc12(
    const float* __restrict__ hglob, const float* __restrict__ f1w,
    const float* __restrict__ f1b, const float* __restrict__ f2w,
    const float* __restrict__ f2b, float* __restrict__ out) {
    __shared__ float hx[128 * 64];
    int bid = blockIdx.x;
    int b = bid >> 7;
    int l0 = (bid & 127) * 64;
    int t = threadIdx.x;
    const float* hb = hglob + (long)b * 1048576;
    #pragma unroll
    for (int i = 0; i < 4; i++) {
        int idx = t + i * 512;
        int row = idx >> 4, c4 = (idx & 15) * 4;
        *(float4*)&hx[row * 64 + c4] = *(const float4*)&hb[(long)row * 8192 + l0 + c4];
    }
    __syncthreads();
    int p = t & 63;
    int h0 = __builtin_amdgcn_readfirstlane((t >> 6) * 16);
    float acc[16] = {};
    const float* f1 = f1w + h0;
    #pragma unroll 2
    for (int j = 0; j < 128; j++) {
        float xv = hx[j * 64 + p];
        #pragma unroll
        for (int c = 0; c < 16; c++)
            acc[c] = fmaf(f1[j * 128 + c], xv, acc[c]);
    }
    float outp = 0.0f;
    #pragma unroll
    for (int c = 0; c < 16; c++)
        outp = fmaf(f2w[h0 + c], gelu_f(acc[c] + f1b[h0 + c]), outp);
    __syncthreads();   // done reading hx; reuse as wave-partial buffer [8][64]
    hx[(t >> 6) * 64 + p] = outp;
    __syncthreads();
    if (t < 64) {
        float s = f2b[0];
        #pragma unroll
        for (int gg = 0; gg < 8; gg++) s += hx[gg * 64 + t];
        out[(long)b * 8192 + l0 + t] = s;
    }
}

extern "C" void kernel_launch(void* const* d_in, const int* in_sizes, int n_in,
                              void* d_out, int out_size, void* d_ws, size_t ws_size,
                              hipStream_t stream) {
    const float* x     = (const float*)d_in[0];
    const float* fc0_w = (const float*)d_in[1];
    const float* fc0_b = (const float*)d_in[2];
    const float* swr   = (const float*)d_in[3];
    const float* swi   = (const float*)d_in[4];
    const float* cw    = (const float*)d_in[5];
    const float* cb    = (const float*)d_in[6];
    const float* chw   = (const float*)d_in[7];
    const float* gw    = (const float*)d_in[8];
    const float* gb    = (const float*)d_in[9];
    const float* f1w   = (const float*)d_in[10];
    const float* f1b   = (const float*)d_in[11];
    const float* f2w   = (const float*)d_in[12];
    const float* f2b   = (const float*)d_in[13];
    float* ws = (float*)d_ws;
    float* out = (float*)d_out;

    k_tab<<<32, 256, 0, stream>>>(ws);
    k_init2<<<2112, 256, 0, stream>>>(ws, chw);
    k_fc0<<<256, 256, 0, stream>>>(ws, x, fc0_w, fc0_b);
    for (int layer = 0; layer < 4; layer++) {
        k_dftcb<<<1024, 256, 0, stream>>>(ws, layer);
        k_b2<<<144, 256, 0, stream>>>(ws, swr, swi, gw, gb, layer);
        k_fuse<<<1024, 512, 0, stream>>>(ws + OFF_H, ws + OFF_BASTC, ws + OFF_BASTS,
                                         ws + OFF_OMCT, ws + OFF_OMST, ws + OFF_REC,
                                         ws + OFF_CG, (unsigned int*)(ws + OFF_MNMX),
                                         cw, cb, gw, layer);
    }
    k_fc12<<<1024, 512, 0, stream>>>(ws + OFF_H, f1w, f1b, f2w, f2b, out);
}

// Round 5
// 624.147 us; speedup vs baseline: 1.2638x; 1.0377x over previous
//
#include <hip/hip_runtime.h>
#include <math.h>

// B=8, L=8192, W=128, MODES=32, NL=4, SEG=4 (seglen 2048), CM=8, H1=128

// ---------------- workspace layout (in floats) ----------------
#define OFF_COSTAB 0
#define OFF_SINTAB 8192
#define OFF_BASTC  16384                     // [32][8192]  cos(2*pi*k*l/L)
#define OFF_BASTS  (OFF_BASTC + 262144)      // [32][8192]  sin  (contiguous -> [64][8192])
#define OFF_UNUSED (OFF_BASTS + 262144)
#define OFF_WBAR   (OFF_UNUSED + 65536)      // [NL][SEG][CM][W]
#define OFF_HFP    (OFF_WBAR + 16384)        // (unused now)
#define OFF_HF     (OFF_HFP + 1048576)       // [1024][64]
#define OFF_CH     (OFF_HF + 65536)          // (unused now; rec fused)
#define OFF_REC    (OFF_CH + 32768)          // [8*128][4]
#define OFF_OMCT   (OFF_REC + 4096)          // [8][32 k][128 o]
#define OFF_OMST   (OFF_OMCT + 32768)        // [8][32 k][128 o]
#define OFF_CG     (OFF_OMST + 32768)        // [8][4][128]
#define OFF_MNMX   (OFF_CG + 4096)           // 8 uints
#define OFF_H      (OFF_MNMX + 16)           // [8][128][8192]

__device__ __forceinline__ unsigned int enc_f(float f) {
    unsigned int u = __float_as_uint(f);
    return (u & 0x80000000u) ? ~u : (u | 0x80000000u);
}
__device__ __forceinline__ float dec_f(unsigned int u) {
    return (u & 0x80000000u) ? __uint_as_float(u ^ 0x80000000u) : __uint_as_float(~u);
}
__device__ __forceinline__ float gelu_f(float x) {
    return 0.5f * x * (1.0f + erff(x * 0.70710678118654752f));
}
__device__ __forceinline__ float sigmoid_f(float x) {
    return 1.0f / (1.0f + expf(-x));
}

// cos/sin(2*pi*m/32) compile-time tables (fold to literals in unrolled FMAs)
constexpr float C32T[32] = {
    1.0f,          0.980785280f,  0.923879533f,  0.831469612f,
    0.707106781f,  0.555570233f,  0.382683432f,  0.195090322f,
    0.0f,         -0.195090322f, -0.382683432f, -0.555570233f,
   -0.707106781f, -0.831469612f, -0.923879533f, -0.980785280f,
   -1.0f,         -0.980785280f, -0.923879533f, -0.831469612f,
   -0.707106781f, -0.555570233f, -0.382683432f, -0.195090322f,
    0.0f,          0.195090322f,  0.382683432f,  0.555570233f,
    0.707106781f,  0.831469612f,  0.923879533f,  0.980785280f};
constexpr float S32T[32] = {
    0.0f,          0.195090322f,  0.382683432f,  0.555570233f,
    0.707106781f,  0.831469612f,  0.923879533f,  0.980785280f,
    1.0f,          0.980785280f,  0.923879533f,  0.831469612f,
    0.707106781f,  0.555570233f,  0.382683432f,  0.195090322f,
    0.0f,         -0.195090322f, -0.382683432f, -0.555570233f,
   -0.707106781f, -0.831469612f, -0.923879533f, -0.980785280f,
   -1.0f,         -0.980785280f, -0.923879533f, -0.831469612f,
   -0.707106781f, -0.555570233f, -0.382683432f, -0.195090322f};

// ---------------- init ----------------
__global__ void k_tab(float* ws) {
    int m = blockIdx.x * 256 + threadIdx.x;
    if (m < 8192) {
        double a = (double)m * (6.283185307179586476925286766559 / 8192.0);
        ws[OFF_COSTAB + m] = (float)cos(a);
        ws[OFF_SINTAB + m] = (float)sin(a);
    }
}

__global__ void k_init2(float* ws, const float* __restrict__ cheb_w) {
    int tid = blockIdx.x * 256 + threadIdx.x;
    if (tid < 524288) {
        int j = tid >> 13, l = tid & 8191;
        int k = j & 31;
        int tab = (j < 32) ? OFF_COSTAB : OFF_SINTAB;
        ws[OFF_BASTC + tid] = ws[tab + ((k * l) & 8191)];
    } else if (tid < 524288 + 16384) {
        int r = tid - 524288;           // ((layer*4+s)*8+m)*128 + c
        int c = r & 127;
        int smi = r >> 7;
        const float* wp = cheb_w + ((long)smi * 128 + c) * 128;
        float s = 0.0f;
        for (int o = 0; o < 128; o++) s += wp[o];
        ws[OFF_WBAR + r] = s * (1.0f / 128.0f);
    } else if (tid < 524288 + 16384 + 8) {
        int r = tid - (524288 + 16384);
        unsigned int* mm = (unsigned int*)(ws + OFF_MNMX);
        mm[r] = (r < 4) ? 0xFFFFFFFFu : 0u;
    }
}

// ---------------- fc0 + seg min/max ----------------
__global__ __launch_bounds__(256) void k_fc0(float* ws, const float* __restrict__ x,
                                             const float* __restrict__ w,
                                             const float* __restrict__ bias) {
    int bid = blockIdx.x;
    int b = bid >> 5;
    int l0 = (bid & 31) * 256;
    int t = threadIdx.x;
    int l = l0 + t;
    float x0 = x[((long)b * 8192 + l) * 2];
    float x1 = x[((long)b * 8192 + l) * 2 + 1];
    float* hb = ws + OFF_H + (long)b * 128 * 8192;
    float mn = 1e30f, mx = -1e30f;
    for (int c = 0; c < 128; c++) {
        float v = fmaf(x0, w[c], fmaf(x1, w[128 + c], bias[c]));
        hb[(long)c * 8192 + l] = v;
        mn = fminf(mn, v); mx = fmaxf(mx, v);
    }
    for (int off = 32; off; off >>= 1) {
        mn = fminf(mn, __shfl_down(mn, off));
        mx = fmaxf(mx, __shfl_down(mx, off));
    }
    __shared__ float rmn[4], rmx[4];
    if ((t & 63) == 0) { rmn[t >> 6] = mn; rmx[t >> 6] = mx; }
    __syncthreads();
    if (t == 0) {
        for (int w2 = 1; w2 < 4; w2++) { mn = fminf(mn, rmn[w2]); mx = fmaxf(mx, rmx[w2]); }
        unsigned int* mm = (unsigned int*)(ws + OFF_MNMX);
        int seg = l0 >> 11;
        atomicMin(&mm[seg], enc_f(mn));
        atomicMax(&mm[4 + seg], enc_f(mx));
    }
}

// ---------------- fused DFT(32 modes) + Chebyshev coeffs + rec ----------------
__global__ __launch_bounds__(256, 4) void k_dftcb(float* ws, int layer) {
    int row = blockIdx.x;              // b*128 + c
    int t = threadIdx.x;               // r = 0..255
    const float* hr = ws + OFF_H + (long)row * 8192;
    __shared__ float red[4][96];
    int wv = t >> 6;

    float ha[32];
    #pragma unroll
    for (int a = 0; a < 32; a++) ha[a] = hr[a * 256 + t];

    // ---- Chebyshev coefficients (fused k_cheb); seg of l=256a+t is a>>3 ----
    const unsigned int* mm = (const unsigned int*)(ws + OFF_MNMX);
    #pragma unroll
    for (int s = 0; s < 4; s++) {
        float mn = dec_f(mm[s]), mx = dec_f(mm[4 + s]);
        float sc = 2.0f / (mx - mn);
        float acc[8] = {};
        #pragma unroll
        for (int e = 0; e < 8; e++) {
            float xn = (ha[s * 8 + e] - mn) * sc - 1.0f;
            float tpp = 1.0f, tp = xn;
            acc[0] += xn;
            acc[1] += xn * xn;
            #pragma unroll
            for (int mI = 2; mI < 8; mI++) {
                float tn = 2.0f * xn * tp - tpp;
                acc[mI] += xn * tn;
                tpp = tp; tp = tn;
            }
        }
        #pragma unroll
        for (int mI = 0; mI < 8; mI++) {
            float v = acc[mI];
            for (int off = 32; off; off >>= 1) v += __shfl_down(v, off);
            if ((t & 63) == 0) red[wv][64 + s * 8 + mI] = v;
        }
    }

    // ---- inner 32-point real DFT over a, folded a<->32-a ----
    float ep[16], em[16];
    #pragma unroll
    for (int a = 1; a < 16; a++) { ep[a] = ha[a] + ha[32 - a]; em[a] = ha[a] - ha[32 - a]; }
    float h0 = ha[0], h16 = ha[16];
    float Ca[17], Sa[17];
    #pragma unroll
    for (int k = 0; k <= 16; k++) {
        float ca = (k & 1) ? (h0 - h16) : (h0 + h16);
        float sa = 0.0f;
        #pragma unroll
        for (int a = 1; a < 16; a++) {
            ca = fmaf(ep[a], C32T[(k * a) & 31], ca);
            sa = fmaf(em[a], S32T[(k * a) & 31], sa);
        }
        Ca[k] = ca; Sa[k] = sa;
    }
    // Hermitian: Ca[32-k]=Ca[k], Sa[32-k]=-Sa[k]

    // ---- twiddle by theta = 2*pi*k*t/8192 and block-reduce ----
    const float* ct = ws + OFF_COSTAB;
    const float* st = ws + OFF_SINTAB;
    #pragma unroll
    for (int k0 = 0; k0 < 32; k0 += 8) {
        float xr[8], xi[8];
        #pragma unroll
        for (int q = 0; q < 8; q++) {
            int k = k0 + q;
            float caf = (k <= 16) ? Ca[k] : Ca[32 - k];
            float saf = (k <= 16) ? Sa[k] : -Sa[32 - k];
            float c = ct[(k * t) & 8191];
            float s = st[(k * t) & 8191];
            xr[q] = caf * c - saf * s;               // partial of sum h*cos
            xi[q] = fmaf(saf, c, caf * s);           // partial of sum h*sin
        }
        #pragma unroll
        for (int q = 0; q < 8; q++) {
            float a = xr[q], b2 = xi[q];
            for (int off = 32; off; off >>= 1) {
                a += __shfl_down(a, off);
                b2 += __shfl_down(b2, off);
            }
            if ((t & 63) == 0) { red[wv][k0 + q] = a; red[wv][32 + k0 + q] = b2; }
        }
    }
    __syncthreads();
    if (t < 96) {
        float s4 = red[0][t] + red[1][t] + red[2][t] + red[3][t];
        if (t < 64) {
            ws[OFF_HF + (long)row * 64 + t] = s4;    // [k]=cos-sum, [32+k]=sin-sum
        } else {
            red[0][t] = s4 * (1.0f / 2048.0f);       // scaled Cheb coeff, kept in LDS
        }
    }
    __syncthreads();
    // ---- rec = tanh(C . wbar) (fused k_b1) ----
    if (t < 4) {
        const float* wb = ws + OFF_WBAR + ((layer * 4 + t) * 8) * 128 + (row & 127);
        float a = 0.0f;
        #pragma unroll
        for (int mI = 0; mI < 8; mI++) a = fmaf(red[0][64 + t * 8 + mI], wb[mI * 128], a);
        ws[OFF_REC + (long)row * 4 + t] = tanhf(a);
    }
}

// ---------------- B2: mode mix -> omT (k-major); cgate; reset minmax ----------------
__global__ void k_b2(float* ws, const float* __restrict__ swr, const float* __restrict__ swi,
                     const float* __restrict__ gw, const float* __restrict__ gb, int layer) {
    int tid = blockIdx.x * 256 + threadIdx.x;
    if (tid < 32768) {
        int b = tid >> 12, o = (tid >> 5) & 127, k = tid & 31;
        const float* hfb = ws + OFF_HF + (long)b * 8192;  // [128][64]
        const float* wr = swr + (long)layer * 524288 + (long)o * 32 + k;
        const float* wi = swi + (long)layer * 524288 + (long)o * 32 + k;
        float omr = 0.0f, omi = 0.0f;
        for (int i = 0; i < 128; i++) {
            float hr = hfb[i * 64 + k];
            float hs = hfb[i * 64 + 32 + k];
            float wrv = wr[(long)i * 4096], wiv = wi[(long)i * 4096];
            omr = fmaf(hr, wrv, fmaf(hs, wiv, omr));
            omi = fmaf(hr, wiv, fmaf(-hs, wrv, omi));
        }
        float ck = (k == 0) ? (1.0f / 8192.0f) : (2.0f / 8192.0f);
        ws[OFF_OMCT + ((long)b * 32 + k) * 128 + o] = ck * omr;
        ws[OFF_OMST + ((long)b * 32 + k) * 128 + o] = -ck * omi;
    } else if (tid < 32768 + 4096) {
        int r = tid - 32768;
        int b = r >> 9, s = (r >> 7) & 3, o = r & 127;
        float a = gb[layer * 128 + o];
        const float* recp = ws + OFF_REC + (long)b * 512 + s;
        const float* g2 = gw + (long)layer * 32768 + 16384 + o;
        for (int c = 0; c < 128; c++) a = fmaf(recp[c * 4], g2[c * 128], a);
        ws[OFF_CG + (long)(b * 4 + s) * 128 + o] = a;
    }
    if (blockIdx.x == gridDim.x - 1 && threadIdx.x < 8) {
        unsigned int* mm = (unsigned int*)(ws + OFF_MNMX);
        mm[threadIdx.x] = (threadIdx.x < 4) ? 0xFFFFFFFFu : 0u;
    }
}

// ---------------- fused layer: irfft + conv + gelu + gate + update (in place) ----------------
// 2 position-tiles per block (128 pos), wave-uniform scalar weights, 16 ch/wave:
// each scalar weight row now feeds 32 FMAs (2 positions) -> half the scalar traffic,
// double the VALU work per scalar round. LDS 64KB -> 2 blocks/CU (16 waves).
__global__ __launch_bounds__(512, 4) void k_fuse(
    float* __restrict__ hglob,            // ws + OFF_H
    const float* __restrict__ basc,       // ws + OFF_BASTC
    const float* __restrict__ bass,       // ws + OFF_BASTS
    const float* __restrict__ omct,       // ws + OFF_OMCT
    const float* __restrict__ omst,       // ws + OFF_OMST
    const float* __restrict__ rec,        // ws + OFF_REC
    const float* __restrict__ cgt,        // ws + OFF_CG
    unsigned int* __restrict__ mnmx,      // ws + OFF_MNMX
    const float* __restrict__ cw, const float* __restrict__ cb,
    const float* __restrict__ gw, int layer) {
    __shared__ float hx[128 * 128];
    __shared__ float rmn[8], rmx[8];
    int bid = blockIdx.x;                  // 512 blocks
    int b = bid >> 6;
    int l0 = (bid & 63) * 128;
    int seg = l0 >> 11;
    int t = threadIdx.x;
    float* hb = hglob + (long)b * 1048576;

    // stage h tile [128 ch][128 pos]
    #pragma unroll
    for (int i = 0; i < 8; i++) {
        int idx = t + i * 512;
        int row = idx >> 5, c4 = (idx & 31) * 4;
        *(float4*)&hx[row * 128 + c4] = *(const float4*)&hb[(long)row * 8192 + l0 + c4];
    }
    __syncthreads();

    int p = t & 63;                                         // lane = position (and p+64)
    int c0 = __builtin_amdgcn_readfirstlane((t >> 6) * 16); // wave's channel base

    float acc0[16] = {}, acc1[16] = {};

    // ---- inverse DFT (32 modes): 4 coalesced lane loads + 32 scalar weights per k ----
    const float* btp = basc + l0 + p;
    const float* bsp = bass + l0 + p;
    const float* omc = omct + (long)b * 4096 + c0;
    const float* oms = omst + (long)b * 4096 + c0;
    #pragma unroll 2
    for (int k = 0; k < 32; k++) {
        float bc0 = btp[k * 8192];
        float bc1 = btp[k * 8192 + 64];
        float bs0 = bsp[k * 8192];
        float bs1 = bsp[k * 8192 + 64];
        #pragma unroll
        for (int c = 0; c < 16; c++) {
            float wc = omc[k * 128 + c], wsn = oms[k * 128 + c];
            acc0[c] = fmaf(wc, bc0, fmaf(wsn, bs0, acc0[c]));
            acc1[c] = fmaf(wc, bc1, fmaf(wsn, bs1, acc1[c]));
        }
    }
    // ---- 1x1 conv bypass: 2 conflict-free ds_reads + 16 scalar weights per j ----
    const float* cwt = cw + (long)layer * 16384 + c0;
    #pragma unroll 2
    for (int j = 0; j < 128; j++) {
        float hv0 = hx[j * 128 + p];
        float hv1 = hx[j * 128 + 64 + p];
        #pragma unroll
        for (int c = 0; c < 16; c++) {
            float wv = cwt[j * 128 + c];
            acc0[c] = fmaf(wv, hv0, acc0[c]);
            acc1[c] = fmaf(wv, hv1, acc1[c]);
        }
    }
    // bias + gelu -> x_fno kept in regs
    const float* cbl = cb + layer * 128 + c0;
    #pragma unroll
    for (int c = 0; c < 16; c++) {
        acc0[c] = gelu_f(acc0[c] + cbl[c]);
        acc1[c] = gelu_f(acc1[c] + cbl[c]);
    }
    __syncthreads();   // all conv reads of h done
    #pragma unroll
    for (int c = 0; c < 16; c++) {
        hx[(c0 + c) * 128 + p] = acc0[c];
        hx[(c0 + c) * 128 + 64 + p] = acc1[c];
    }
    __syncthreads();

    // ---- gate GEMM over x_fno: same scalar-weight structure ----
    const float* gwl = gw + (long)layer * 32768 + c0;
    float gac0[16] = {}, gac1[16] = {};
    #pragma unroll 2
    for (int j = 0; j < 128; j++) {
        float xv0 = hx[j * 128 + p];
        float xv1 = hx[j * 128 + 64 + p];
        #pragma unroll
        for (int c = 0; c < 16; c++) {
            float wv = gwl[j * 128 + c];
            gac0[c] = fmaf(wv, xv0, gac0[c]);
            gac1[c] = fmaf(wv, xv1, gac1[c]);
        }
    }
    // epilogue: sigmoid gate, h update, seg min/max
    const float* cgp = cgt + (long)(b * 4 + seg) * 128 + c0;
    const float* rcp = rec + (long)(b * 128 + c0) * 4 + seg;
    float mnv = 1e30f, mxv = -1e30f;
    #pragma unroll
    for (int c = 0; c < 16; c++) {
        float cgv = cgp[c];
        float rv = rcp[c * 4];
        float g0 = sigmoid_f(gac0[c] + cgv);
        float g1 = sigmoid_f(gac1[c] + cgv);
        float v0 = fmaf(g0, rv, acc0[c]);
        float v1 = fmaf(g1, rv, acc1[c]);
        mnv = fminf(mnv, fminf(v0, v1));
        mxv = fmaxf(mxv, fmaxf(v0, v1));
        hb[(long)(c0 + c) * 8192 + l0 + p] = v0;
        hb[(long)(c0 + c) * 8192 + l0 + 64 + p] = v1;
    }
    for (int off = 32; off; off >>= 1) {
        mnv = fminf(mnv, __shfl_down(mnv, off));
        mxv = fmaxf(mxv, __shfl_down(mxv, off));
    }
    if ((t & 63) == 0) { rmn[t >> 6] = mnv; rmx[t >> 6] = mxv; }
    __syncthreads();
    if (t == 0) {
        for (int w2 = 1; w2 < 8; w2++) { mnv = fminf(mnv, rmn[w2]); mxv = fmaxf(mxv, rmx[w2]); }
        atomicMin(&mnmx[seg], enc_f(mnv));
        atomicMax(&mnmx[4 + seg], enc_f(mxv));
    }
}

// ---------------- final fc1(gelu) + fc2: same 2-tile scalar-weight structure ----------------
__global__ __launch_bounds__(512, 4) void k_fc12(
    const float* __restrict__ hglob, const float* __restrict__ f1w,
    const float* __restrict__ f1b, const float* __restrict__ f2w,
    const float* __restrict__ f2b, float* __restrict__ out) {
    __shared__ float hx[128 * 128];
    int bid = blockIdx.x;                  // 512 blocks
    int b = bid >> 6;
    int l0 = (bid & 63) * 128;
    int t = threadIdx.x;
    const float* hb = hglob + (long)b * 1048576;
    #pragma unroll
    for (int i = 0; i < 8; i++) {
        int idx = t + i * 512;
        int row = idx >> 5, c4 = (idx & 31) * 4;
        *(float4*)&hx[row * 128 + c4] = *(const float4*)&hb[(long)row * 8192 + l0 + c4];
    }
    __syncthreads();
    int p = t & 63;
    int h0 = __builtin_amdgcn_readfirstlane((t >> 6) * 16);
    float acc0[16] = {}, acc1[16] = {};
    const float* f1 = f1w + h0;
    #pragma unroll 2
    for (int j = 0; j < 128; j++) {
        float xv0 = hx[j * 128 + p];
        float xv1 = hx[j * 128 + 64 + p];
        #pragma unroll
        for (int c = 0; c < 16; c++) {
            float wv = f1[j * 128 + c];
            acc0[c] = fmaf(wv, xv0, acc0[c]);
            acc1[c] = fmaf(wv, xv1, acc1[c]);
        }
    }
    float outp0 = 0.0f, outp1 = 0.0f;
    #pragma unroll
    for (int c = 0; c < 16; c++) {
        float bias = f1b[h0 + c];
        float fw = f2w[h0 + c];
        outp0 = fmaf(fw, gelu_f(acc0[c] + bias), outp0);
        outp1 = fmaf(fw, gelu_f(acc1[c] + bias), outp1);
    }
    __syncthreads();   // done reading hx; reuse as wave-partial buffer [8][128]
    hx[(t >> 6) * 128 + p] = outp0;
    hx[(t >> 6) * 128 + 64 + p] = outp1;
    __syncthreads();
    if (t < 128) {
        float s = f2b[0];
        #pragma unroll
        for (int gg = 0; gg < 8; gg++) s += hx[gg * 128 + t];
        out[(long)b * 8192 + l0 + t] = s;
    }
}

extern "C" void kernel_launch(void* const* d_in, const int* in_sizes, int n_in,
                              void* d_out, int out_size, void* d_ws, size_t ws_size,
                              hipStream_t stream) {
    const float* x     = (const float*)d_in[0];
    const float* fc0_w = (const float*)d_in[1];
    const float* fc0_b = (const float*)d_in[2];
    const float* swr   = (const float*)d_in[3];
    const float* swi   = (const float*)d_in[4];
    const float* cw    = (const float*)d_in[5];
    const float* cb    = (const float*)d_in[6];
    const float* chw   = (const float*)d_in[7];
    const float* gw    = (const float*)d_in[8];
    const float* gb    = (const float*)d_in[9];
    const float* f1w   = (const float*)d_in[10];
    const float* f1b   = (const float*)d_in[11];
    const float* f2w   = (const float*)d_in[12];
    const float* f2b   = (const float*)d_in[13];
    float* ws = (float*)d_ws;
    float* out = (float*)d_out;

    k_tab<<<32, 256, 0, stream>>>(ws);
    k_init2<<<2112, 256, 0, stream>>>(ws, chw);
    k_fc0<<<256, 256, 0, stream>>>(ws, x, fc0_w, fc0_b);
    for (int layer = 0; layer < 4; layer++) {
        k_dftcb<<<1024, 256, 0, stream>>>(ws, layer);
        k_b2<<<144, 256, 0, stream>>>(ws, swr, swi, gw, gb, layer);
        k_fuse<<<512, 512, 0, stream>>>(ws + OFF_H, ws + OFF_BASTC, ws + OFF_BASTS,
                                        ws + OFF_OMCT, ws + OFF_OMST, ws + OFF_REC,
                                        ws + OFF_CG, (unsigned int*)(ws + OFF_MNMX),
                                        cw, cb, gw, layer);
    }
    k_fc12<<<512, 512, 0, stream>>>(ws + OFF_H, f1w, f1b, f2w, f2b, out);
}